// Round 9
// baseline (553.558 us; speedup 1.0000x reference)
//
#include <hip/hip_runtime.h>
#include <hip/hip_bf16.h>
#include <hip/hip_cooperative_groups.h>

namespace cg = cooperative_groups;

#define NN 50000
#define NP 50001  // row stride incl. zero-row at index NN
#define NE 800000
#define FD 256
#define LD 128
#define BN_EPS 1e-5f
#define NEPAD (NE + 7 * NN + 16)

typedef __bf16 bf16_t;
typedef bf16_t bf16x8 __attribute__((ext_vector_type(8)));
typedef float f32x4 __attribute__((ext_vector_type(4)));
typedef float f32x2 __attribute__((ext_vector_type(2)));
typedef int i32x2 __attribute__((ext_vector_type(2)));
typedef int i32x4 __attribute__((ext_vector_type(4)));
typedef unsigned int u32x4 __attribute__((ext_vector_type(4)));
typedef unsigned short u16x8 __attribute__((ext_vector_type(8)));

// ---------------- fused CSR build + weight convert (cooperative) ----------
// 256 blocks x 256 threads, phases separated by grid.sync():
// P0 zero counters || swizzle weights; P1 degree count; P2 block scan;
// P3 cross-block scan; P4 finalize row_ptr/dinv/pad/histogram (descending
// degree bins -> LPT schedule for spmm); P5 order || fill.
__global__ __launch_bounds__(256) void k_build(
    const int* __restrict__ src, const int* __restrict__ dst,
    int* __restrict__ cnt, int* __restrict__ cursor, int* __restrict__ row_ptr,
    int* __restrict__ partials, float* __restrict__ dinv,
    unsigned short* __restrict__ col, int* __restrict__ hist,
    int* __restrict__ rank, int* __restrict__ order, i32x2* __restrict__ desc,
    float* __restrict__ dinvp, const float* __restrict__ W0,
    const float* __restrict__ W1, const float* __restrict__ Wmu,
    const float* __restrict__ bmu, const float* __restrict__ Wlv,
    const float* __restrict__ blv, bf16_t* __restrict__ W0s,
    bf16_t* __restrict__ W1s, bf16_t* __restrict__ Whs,
    float* __restrict__ biash, bf16_t* __restrict__ g16,
    bf16_t* __restrict__ agg16) {
  cg::grid_group grid = cg::this_grid();
  __shared__ int s0[64], s1[64], s2[64];
  const int t = threadIdx.x, b = blockIdx.x;
  const int gtid = b * 256 + t;
  const int GT = 256 * 256;

  // ---- P0: zero cnt|cursor|statsAll|hist|rank (contiguous) + convw ----
  for (int i = gtid; i < 2 * NN + 1152; i += GT) cnt[i] = 0;
  {
    int k = b, n = t;
    int chunk = (n >> 4) * 8 + (k >> 5);
    int slot = ((k >> 3) & 3) * 16 + (n & 15);
    int idx = chunk * 512 + slot * 8 + (k & 7);
    W0s[idx] = (bf16_t)W0[k * 256 + n];
    W1s[idx] = (bf16_t)W1[k * 256 + n];
    float wh = (n < 128) ? Wmu[k * 128 + n] : Wlv[k * 128 + (n - 128)];
    Whs[idx] = (bf16_t)wh;
    if (k == 0) biash[n] = (n < 128) ? bmu[n] : blv[n - 128];
    if (k == 1) {
      int ss = n >> 6, j = n & 63;
      g16[((size_t)ss * NP + NN) * 64 + j] = (bf16_t)0.f;
      agg16[((size_t)ss * NP + NN) * 64 + j] = (bf16_t)0.f;
    }
  }
  grid.sync();

  // ---- P1: degree count ----
  for (int i = gtid; i < NE; i += GT) atomicAdd(&cnt[dst[i]], 1);
  grid.sync();

  // ---- P2: per-block scan of padded counts (blocks 0..48, 1024 each) ----
  if (b < 49) {
    int base = b * 1024 + t * 4;
    int vals[4];
#pragma unroll
    for (int j = 0; j < 4; ++j)
      vals[j] = (base + j < NN) ? ((cnt[base + j] + 7) & ~7) : 0;
    int tsum = vals[0] + vals[1] + vals[2] + vals[3];
    int lane = t & 63, wid = t >> 6;
    int x = tsum;
#pragma unroll
    for (int off = 1; off < 64; off <<= 1) {
      int y = __shfl_up(x, off, 64);
      if (lane >= off) x += y;
    }
    if (lane == 63) s0[wid] = x;
    __syncthreads();
    int woff = 0;
    for (int w = 0; w < wid; ++w) woff += s0[w];
    int run = woff + x - tsum;
#pragma unroll
    for (int j = 0; j < 4; ++j) {
      if (base + j < NN) row_ptr[base + j] = run;
      run += vals[j];
    }
    if (t == 255) partials[b] = woff + x;
  }
  grid.sync();

  // ---- P3: scan the 49 block partials (block 0, one wave) ----
  if (b == 0 && t < 64) {
    int v = (t < 49) ? partials[t] : 0;
    int x = v;
#pragma unroll
    for (int off = 1; off < 64; off <<= 1) {
      int y = __shfl_up(x, off, 64);
      if (t >= off) x += y;
    }
    if (t < 49) partials[t] = x - v;
    if (t == 48) row_ptr[NN] = x;  // total padded edges
  }
  grid.sync();

  // ---- P4: finalize row_ptr, dinv, pad col, histogram (descending) ----
  if (t < 64) s0[t] = 0;
  __syncthreads();
  if (b < 49) {
    int off = partials[b];
    int base = b * 1024 + t * 4;
#pragma unroll
    for (int j = 0; j < 4; ++j)
      if (base + j < NN) {
        int deg = cnt[base + j];
        int rp = row_ptr[base + j] + off;
        row_ptr[base + j] = rp;
        dinv[base + j] = rsqrtf(1.0f + (float)deg);
        int pd = (deg + 7) & ~7;
        for (int p = deg; p < pd; ++p) col[rp + p] = (unsigned short)NN;
        int it = pd >> 3;
        if (it > 63) it = 63;
        atomicAdd(&s0[63 - it], 1);  // descending-degree bin
      }
    __syncthreads();
    if (t < 64 && s0[t]) atomicAdd(&hist[t], s0[t]);
  }
  grid.sync();

  // ---- P5a: scatter rows into degree-DESCENDING order ----
  {
    if (t < 64) {
      s0[t] = 0;
      int v = hist[t];
      int x = v;
#pragma unroll
      for (int off = 1; off < 64; off <<= 1) {
        int y = __shfl_up(x, off, 64);
        if (t >= off) x += y;
      }
      s2[t] = x - v;  // exclusive scan of bins
    }
    __syncthreads();
    int i = gtid;
    int bin = 0, rloc = 0, pd = 0;
    bool valid = (i < NN);
    if (valid) {
      pd = (cnt[i] + 7) & ~7;
      int it = pd >> 3;
      if (it > 63) it = 63;
      bin = 63 - it;
      rloc = atomicAdd(&s0[bin], 1);
    }
    __syncthreads();
    if (t < 64 && s0[t]) s1[t] = s2[t] + atomicAdd(&rank[t], s0[t]);
    __syncthreads();
    if (valid) {
      int p = s1[bin] + rloc;
      order[p] = i;
      int rp = row_ptr[i];
      desc[p] = (i32x2){rp, rp + pd};
      dinvp[p] = dinv[i];
    }
  }
  // ---- P5b: fill CSR columns (u16) ----
  for (int i = gtid; i < NE; i += GT) {
    int d = dst[i];
    int p = atomicAdd(&cursor[d], 1);
    col[row_ptr[d] + p] = (unsigned short)src[i];
  }
}

// ---------------- barrier-free LDS-free MFMA GEMM -------------------------
// Each wave owns 16 rows x 128 cols (half = blockIdx.y). B-fragments are
// read DIRECTLY from swizzled global W (L2-hot 128 KB) -- no LDS staging,
// no barrier, occupancy VGPR-bound. bf16 activations (a_f32==0) in
// SUPERSLICE layout [4][NP][64]. BN finalize fused via stats.
__global__ __launch_bounds__(256) void k_mgemm(
    const void* __restrict__ Ap, int a_f32, const bf16_t* __restrict__ Wswz,
    bf16_t* __restrict__ Cb, float* __restrict__ Cf, int M,
    const float* __restrict__ stats, const float* __restrict__ gamma,
    const float* __restrict__ beta, const float* __restrict__ row_scale,
    const float* __restrict__ col_bias, int split) {
  __shared__ float bnsc_l[256], bnsh_l[256];
  const int tid = threadIdx.x;
  const int half = blockIdx.y;
  if (stats) {
    float mean = stats[tid] * (1.0f / NN);
    float var = stats[256 + tid] * (1.0f / NN) - mean * mean;
    float rs = rsqrtf(var + BN_EPS);
    float sc = gamma[tid] * rs;
    bnsc_l[tid] = sc;
    bnsh_l[tid] = beta[tid] - mean * sc;
    __syncthreads();
  }

  const int wave = tid >> 6, lane = tid & 63;
  const int m = lane & 15, q = lane >> 4;  // A-frag: row m, k-octet q
  const int row0 = blockIdx.x * 64 + wave * 16;
  const int rg = row0 + m;
  const int rc = rg < M ? rg : M - 1;

  bf16x8 af[8];
  if (a_f32) {
    const float* p = (const float*)Ap + (size_t)rc * 256 + q * 8;
    float4 f0[8], f1[8];
#pragma unroll
    for (int kb = 0; kb < 8; ++kb) {
      f0[kb] = *(const float4*)(p + kb * 32);
      f1[kb] = *(const float4*)(p + kb * 32 + 4);
    }
#pragma unroll
    for (int kb = 0; kb < 8; ++kb) {
      bf16x8 fr;
      fr[0] = (bf16_t)f0[kb].x; fr[1] = (bf16_t)f0[kb].y;
      fr[2] = (bf16_t)f0[kb].z; fr[3] = (bf16_t)f0[kb].w;
      fr[4] = (bf16_t)f1[kb].x; fr[5] = (bf16_t)f1[kb].y;
      fr[6] = (bf16_t)f1[kb].z; fr[7] = (bf16_t)f1[kb].w;
      af[kb] = fr;
    }
  } else {
    const bf16_t* pA = (const bf16_t*)Ap;
    bf16x8 raw[8];
#pragma unroll
    for (int kb = 0; kb < 8; ++kb)
      raw[kb] = *(const bf16x8*)&pA[((size_t)(kb >> 1) * NP + rc) * 64 +
                                    (kb & 1) * 32 + q * 8];
#pragma unroll
    for (int kb = 0; kb < 8; ++kb) {
      float s[8], h[8];
      if (stats) {
        float4 s0 = *(const float4*)&bnsc_l[kb * 32 + q * 8];
        float4 s1 = *(const float4*)&bnsc_l[kb * 32 + q * 8 + 4];
        float4 h0 = *(const float4*)&bnsh_l[kb * 32 + q * 8];
        float4 h1 = *(const float4*)&bnsh_l[kb * 32 + q * 8 + 4];
        s[0] = s0.x; s[1] = s0.y; s[2] = s0.z; s[3] = s0.w;
        s[4] = s1.x; s[5] = s1.y; s[6] = s1.z; s[7] = s1.w;
        h[0] = h0.x; h[1] = h0.y; h[2] = h0.z; h[3] = h0.w;
        h[4] = h1.x; h[5] = h1.y; h[6] = h1.z; h[7] = h1.w;
      }
      bf16x8 r = raw[kb];
      bf16x8 fr;
#pragma unroll
      for (int j = 0; j < 8; ++j) {
        float v = (float)r[j];
        if (stats) v = fmaxf(fmaf(v, s[j], h[j]), 0.f);
        fr[j] = (bf16_t)v;
      }
      af[kb] = fr;
    }
  }

  const bf16_t* Wb = Wswz + (size_t)half * 64 * 512 + lane * 8;
  f32x4 acc[8] = {};
#pragma unroll
  for (int nt = 0; nt < 8; ++nt) {
#pragma unroll
    for (int kb = 0; kb < 8; ++kb) {
      bf16x8 b = *(const bf16x8*)&Wb[(nt * 8 + kb) * 512];
      acc[nt] =
          __builtin_amdgcn_mfma_f32_16x16x32_bf16(af[kb], b, acc[nt], 0, 0, 0);
    }
  }

  // epilogue: D row_local = q*4 + r, col_local = m  [m89-verified layout]
#pragma unroll
  for (int r = 0; r < 4; ++r) {
    int row = row0 + q * 4 + r;
    if (row >= M) continue;
    float rs = row_scale ? row_scale[row] : 1.0f;
#pragma unroll
    for (int nt = 0; nt < 8; ++nt) {
      int col = half * 128 + nt * 16 + m;
      float v = acc[nt][r] * rs;
      if (col_bias) v += col_bias[col];
      if (Cb) {
        Cb[((size_t)(col >> 6) * NP + row) * 64 + (col & 63)] = (bf16_t)v;
      } else if (!split) {
        Cf[(size_t)row * 256 + col] = v;
      } else {
        if (col < 128)
          Cf[(size_t)row * 128 + col] = v;
        else
          Cf[(size_t)(M + row) * 128 + (col - 128)] = v;
      }
    }
  }
}

// ---------------- SpMM + fused BN stats, XCD-pair superslices -------------
// g / out superslice-major [4][NP][64]. slice = blockIdx.x & 3. Teams of 8
// lanes (16 B/lane -> ONE 128 B line per gather), TWO degree-sorted rows
// per team (DESCENDING degree: heavy blocks first = LPT). col is u16.
#define ACCUM8(A, d)                                             \
  A[0] += (f32x2){__uint_as_float(d[0] << 16),                   \
                  __uint_as_float(d[0] & 0xffff0000u)};          \
  A[1] += (f32x2){__uint_as_float(d[1] << 16),                   \
                  __uint_as_float(d[1] & 0xffff0000u)};          \
  A[2] += (f32x2){__uint_as_float(d[2] << 16),                   \
                  __uint_as_float(d[2] & 0xffff0000u)};          \
  A[3] += (f32x2){__uint_as_float(d[3] << 16),                   \
                  __uint_as_float(d[3] & 0xffff0000u)};

__global__ __launch_bounds__(256) void k_spmm(
    const bf16_t* __restrict__ g, const int* __restrict__ order,
    const i32x2* __restrict__ desc, const unsigned short* __restrict__ col,
    const float* __restrict__ dinvp, bf16_t* __restrict__ out,
    float* __restrict__ stats) {
  __shared__ float sbuf[32][64];
  const int s = blockIdx.x & 3;
  const int grp = blockIdx.x >> 2;
  const int team = threadIdx.x >> 3, tl = threadIdx.x & 7;
  const int slotA = grp * 64 + team * 2;  // even; NN even -> A,B same validity
  const u32x4* gu = (const u32x4*)(g + (size_t)s * NP * 64);  // node*8 + tl
  float s1[8] = {}, s2[8] = {};
  if (slotA < NN) {
    f32x2 accA[4] = {}, accB[4] = {};
    i32x2 o2 = *(const i32x2*)&order[slotA];
    i32x4 d4 = *(const i32x4*)&desc[slotA];
    f32x2 dv2 = *(const f32x2*)&dinvp[slotA];
    int dstA = o2[0], dstB = o2[1];
    int bA = d4[0], eA = d4[1], bB = d4[2], eB = d4[3];
    {
      u32x4 dA = gu[(size_t)dstA * 8 + tl];
      u32x4 dB = gu[(size_t)dstB * 8 + tl];
      ACCUM8(accA, dA)
      ACCUM8(accB, dB)
    }
    u16x8 cA = {}, cB = {};
    if (bA < eA) cA = __builtin_nontemporal_load((const u16x8*)&col[bA]);
    if (bB < eB) cB = __builtin_nontemporal_load((const u16x8*)&col[bB]);
    while (bA < eA && bB < eB) {
      u32x4 wa0 = gu[(size_t)cA[0] * 8 + tl];
      u32x4 wa1 = gu[(size_t)cA[1] * 8 + tl];
      u32x4 wa2 = gu[(size_t)cA[2] * 8 + tl];
      u32x4 wa3 = gu[(size_t)cA[3] * 8 + tl];
      u32x4 wa4 = gu[(size_t)cA[4] * 8 + tl];
      u32x4 wa5 = gu[(size_t)cA[5] * 8 + tl];
      u32x4 wa6 = gu[(size_t)cA[6] * 8 + tl];
      u32x4 wa7 = gu[(size_t)cA[7] * 8 + tl];
      u32x4 wb0 = gu[(size_t)cB[0] * 8 + tl];
      u32x4 wb1 = gu[(size_t)cB[1] * 8 + tl];
      u32x4 wb2 = gu[(size_t)cB[2] * 8 + tl];
      u32x4 wb3 = gu[(size_t)cB[3] * 8 + tl];
      u32x4 wb4 = gu[(size_t)cB[4] * 8 + tl];
      u32x4 wb5 = gu[(size_t)cB[5] * 8 + tl];
      u32x4 wb6 = gu[(size_t)cB[6] * 8 + tl];
      u32x4 wb7 = gu[(size_t)cB[7] * 8 + tl];
      int bnA = bA + 8, bnB = bB + 8;
      u16x8 cnA = {}, cnB = {};
      if (bnA < eA) cnA = __builtin_nontemporal_load((const u16x8*)&col[bnA]);
      if (bnB < eB) cnB = __builtin_nontemporal_load((const u16x8*)&col[bnB]);
      ACCUM8(accA, wa0) ACCUM8(accA, wa1) ACCUM8(accA, wa2) ACCUM8(accA, wa3)
      ACCUM8(accA, wa4) ACCUM8(accA, wa5) ACCUM8(accA, wa6) ACCUM8(accA, wa7)
      ACCUM8(accB, wb0) ACCUM8(accB, wb1) ACCUM8(accB, wb2) ACCUM8(accB, wb3)
      ACCUM8(accB, wb4) ACCUM8(accB, wb5) ACCUM8(accB, wb6) ACCUM8(accB, wb7)
      cA = cnA;
      cB = cnB;
      bA = bnA;
      bB = bnB;
    }
    while (bA < eA) {  // A tail
      u32x4 w0 = gu[(size_t)cA[0] * 8 + tl];
      u32x4 w1 = gu[(size_t)cA[1] * 8 + tl];
      u32x4 w2 = gu[(size_t)cA[2] * 8 + tl];
      u32x4 w3 = gu[(size_t)cA[3] * 8 + tl];
      u32x4 w4 = gu[(size_t)cA[4] * 8 + tl];
      u32x4 w5 = gu[(size_t)cA[5] * 8 + tl];
      u32x4 w6 = gu[(size_t)cA[6] * 8 + tl];
      u32x4 w7 = gu[(size_t)cA[7] * 8 + tl];
      int bn = bA + 8;
      u16x8 cn = {};
      if (bn < eA) cn = __builtin_nontemporal_load((const u16x8*)&col[bn]);
      ACCUM8(accA, w0) ACCUM8(accA, w1) ACCUM8(accA, w2) ACCUM8(accA, w3)
      ACCUM8(accA, w4) ACCUM8(accA, w5) ACCUM8(accA, w6) ACCUM8(accA, w7)
      cA = cn;
      bA = bn;
    }
    while (bB < eB) {  // B tail
      u32x4 w0 = gu[(size_t)cB[0] * 8 + tl];
      u32x4 w1 = gu[(size_t)cB[1] * 8 + tl];
      u32x4 w2 = gu[(size_t)cB[2] * 8 + tl];
      u32x4 w3 = gu[(size_t)cB[3] * 8 + tl];
      u32x4 w4 = gu[(size_t)cB[4] * 8 + tl];
      u32x4 w5 = gu[(size_t)cB[5] * 8 + tl];
      u32x4 w6 = gu[(size_t)cB[6] * 8 + tl];
      u32x4 w7 = gu[(size_t)cB[7] * 8 + tl];
      int bn = bB + 8;
      u16x8 cn = {};
      if (bn < eB) cn = __builtin_nontemporal_load((const u16x8*)&col[bn]);
      ACCUM8(accB, w0) ACCUM8(accB, w1) ACCUM8(accB, w2) ACCUM8(accB, w3)
      ACCUM8(accB, w4) ACCUM8(accB, w5) ACCUM8(accB, w6) ACCUM8(accB, w7)
      cB = cn;
      bB = bn;
    }
    float dvA = dv2[0], dvB = dv2[1];
    bf16x8 ovA, ovB;
#pragma unroll
    for (int j = 0; j < 8; ++j) {
      ovA[j] = (bf16_t)(accA[j >> 1][j & 1] * dvA);
      ovB[j] = (bf16_t)(accB[j >> 1][j & 1] * dvB);
    }
    __builtin_nontemporal_store(
        ovA, (bf16x8*)&out[((size_t)s * NP + dstA) * 64 + (size_t)tl * 8]);
    __builtin_nontemporal_store(
        ovB, (bf16x8*)&out[((size_t)s * NP + dstB) * 64 + (size_t)tl * 8]);
#pragma unroll
    for (int j = 0; j < 8; ++j) {
      float va = (float)ovA[j], vb = (float)ovB[j];
      s1[j] += va + vb;
      s2[j] = fmaf(va, va, s2[j]);
      s2[j] = fmaf(vb, vb, s2[j]);
    }
  }
  // block reduction of stats (64 feats of this slice across 32 teams)
#pragma unroll
  for (int j = 0; j < 8; ++j) sbuf[team][tl * 8 + j] = s1[j];
  __syncthreads();
  if (threadIdx.x < 64) {
    float tot = 0.f;
#pragma unroll
    for (int w = 0; w < 32; ++w) tot += sbuf[w][threadIdx.x];
    atomicAdd(&stats[s * 64 + threadIdx.x], tot);
  }
  __syncthreads();
#pragma unroll
  for (int j = 0; j < 8; ++j) sbuf[team][tl * 8 + j] = s2[j];
  __syncthreads();
  if (threadIdx.x < 64) {
    float tot = 0.f;
#pragma unroll
    for (int w = 0; w < 32; ++w) tot += sbuf[w][threadIdx.x];
    atomicAdd(&stats[256 + s * 64 + threadIdx.x], tot);
  }
}

// ---------------- launch ----------------
extern "C" void kernel_launch(void* const* d_in, const int* in_sizes, int n_in,
                              void* d_out, int out_size, void* d_ws, size_t ws_size,
                              hipStream_t stream) {
  const float* x = (const float*)d_in[0];
  const int* ei = (const int*)d_in[1];
  const int* esrc = ei;
  const int* edst = ei + NE;
  const float* W0 = (const float*)d_in[2];
  const float* gamma0 = (const float*)d_in[4];
  const float* beta0 = (const float*)d_in[5];
  const float* W1 = (const float*)d_in[6];
  const float* gamma1 = (const float*)d_in[8];
  const float* beta1 = (const float*)d_in[9];
  const float* W_mu = (const float*)d_in[10];
  const float* b_mu = (const float*)d_in[11];
  const float* W_lv = (const float*)d_in[12];
  const float* b_lv = (const float*)d_in[13];
  float* out = (float*)d_out;

  // workspace carve: cnt|cursor|statsAll|hist|rank contiguous (zeroed in P0)
  bf16_t* g16 = (bf16_t*)d_ws;                        // 4*NP*64 (superslice)
  bf16_t* agg16 = g16 + (size_t)4 * NP * 64;          // 4*NP*64 (superslice)
  int* cnt = (int*)(agg16 + (size_t)4 * NP * 64);     // NN
  int* cursor = cnt + NN;                             // NN
  float* statsAll = (float*)(cursor + NN);            // 1024 (2 layers x 512)
  int* hist = (int*)(statsAll + 1024);                // 64
  int* rank = hist + 64;                              // 64
  float* dinv = (float*)(rank + 64);                  // NN
  float* biash = dinv + NN;                           // 256
  bf16_t* W0s = (bf16_t*)(biash + 256);               // 65536 each
  bf16_t* W1s = W0s + 256 * 256;
  bf16_t* Whs = W1s + 256 * 256;
  int* row_ptr = (int*)(Whs + 256 * 256);             // NN+4
  int* order = row_ptr + NN + 4;                      // NN
  float* dinvp = (float*)(order + NN);                // NN
  i32x2* desc = (i32x2*)(dinvp + NN);                 // NN (8 B each)
  unsigned short* col = (unsigned short*)(desc + NN); // NEPAD u16 (16B align)
  int* partials = (int*)(col + NEPAD);                // 64

  {
    void* args[] = {&esrc, &edst, &cnt,   &cursor, &row_ptr, &partials, &dinv,
                    &col,  &hist, &rank,  &order,  &desc,    &dinvp,    &W0,
                    &W1,   &W_mu, &b_mu,  &W_lv,   &b_lv,    &W0s,      &W1s,
                    &Whs,  &biash, &g16,  &agg16};
    hipLaunchCooperativeKernel((void*)k_build, dim3(256), dim3(256), args, 0,
                               stream);
  }

  dim3 gg((NN + 63) / 64, 2);  // 782 x 2 = 1564 blocks, 16 rows/wave
  const int SPMM_BLKS = 4 * ((NN + 63) / 64);  // 3128, slice = bid & 3

  // layer 0
  k_mgemm<<<gg, 256, 0, stream>>>(x, 1, W0s, g16, nullptr, NN, nullptr, nullptr,
                                  nullptr, dinv, nullptr, 0);
  k_spmm<<<SPMM_BLKS, 256, 0, stream>>>(g16, order, desc, col, dinvp, agg16,
                                        statsAll);

  // layer 1 (BN finalize of layer 0 fused into mgemm)
  k_mgemm<<<gg, 256, 0, stream>>>(agg16, 0, W1s, g16, nullptr, NN, statsAll,
                                  gamma0, beta0, dinv, nullptr, 0);
  k_spmm<<<SPMM_BLKS, 256, 0, stream>>>(g16, order, desc, col, dinvp, agg16,
                                        statsAll + 512);

  // heads (fused mu|logvar; BN finalize of layer 1 fused)
  k_mgemm<<<gg, 256, 0, stream>>>(agg16, 0, Whs, nullptr, out, NN,
                                  statsAll + 512, gamma1, beta1, nullptr, biash,
                                  1);
}

// Round 10
// 458.666 us; speedup vs baseline: 1.2069x; 1.2069x over previous
//
#include <hip/hip_runtime.h>
#include <hip/hip_bf16.h>

#define NN 50000
#define NP 50001  // row stride incl. zero-row at index NN
#define NE 800000
#define FD 256
#define LD 128
#define BN_EPS 1e-5f
#define NEPAD (NE + 7 * NN + 16)
#define CNT_BLKS 3125   // NE/256
#define ORD_BLKS 196    // ceil(NN/256)

typedef __bf16 bf16_t;
typedef bf16_t bf16x8 __attribute__((ext_vector_type(8)));
typedef float f32x4 __attribute__((ext_vector_type(4)));
typedef float f32x2 __attribute__((ext_vector_type(2)));
typedef int i32x2 __attribute__((ext_vector_type(2)));
typedef int i32x4 __attribute__((ext_vector_type(4)));
typedef unsigned int u32x4 __attribute__((ext_vector_type(4)));
typedef unsigned short u16x8 __attribute__((ext_vector_type(8)));

// ---------------- D2: degree count || weight swizzle ----------------------
__global__ __launch_bounds__(256) void k_countw(
    const int* __restrict__ dst, int* __restrict__ cnt,
    const float* __restrict__ W0, const float* __restrict__ W1,
    const float* __restrict__ Wmu, const float* __restrict__ bmu,
    const float* __restrict__ Wlv, const float* __restrict__ blv,
    bf16_t* __restrict__ W0s, bf16_t* __restrict__ W1s,
    bf16_t* __restrict__ Whs, float* __restrict__ biash,
    bf16_t* __restrict__ g16, bf16_t* __restrict__ agg16) {
  int b = blockIdx.x, t = threadIdx.x;
  if (b < CNT_BLKS) {
    int i = b * 256 + t;
    if (i < NE) atomicAdd(&cnt[dst[i]], 1);
  } else {
    int k = b - CNT_BLKS, n = t;
    int chunk = (n >> 4) * 8 + (k >> 5);
    int slot = ((k >> 3) & 3) * 16 + (n & 15);
    int idx = chunk * 512 + slot * 8 + (k & 7);
    W0s[idx] = (bf16_t)W0[k * 256 + n];
    W1s[idx] = (bf16_t)W1[k * 256 + n];
    float wh = (n < 128) ? Wmu[k * 128 + n] : Wlv[k * 128 + (n - 128)];
    Whs[idx] = (bf16_t)wh;
    if (k == 0) biash[n] = (n < 128) ? bmu[n] : blv[n - 128];
    if (k == 1) {
      int ss = n >> 6, j = n & 63;
      g16[((size_t)ss * NP + NN) * 64 + j] = (bf16_t)0.f;
      agg16[((size_t)ss * NP + NN) * 64 + j] = (bf16_t)0.f;
    }
  }
}

// ---------------- D3: single-block full scan ------------------------------
// One 1024-thread block: padded-degree exclusive scan over all NN rows
// (13 chunks of 4096), writes row_ptr/dinv, pads col with zero-row, builds
// the descending-degree histogram in LDS, and emits its exclusive scan
// (binoff). 50k-scale work -> ~15 us on one CU; no grid sync needed.
__global__ __launch_bounds__(1024) void k_scan(const int* __restrict__ cnt,
                                               int* __restrict__ row_ptr,
                                               float* __restrict__ dinv,
                                               unsigned short* __restrict__ col,
                                               int* __restrict__ binoff) {
  __shared__ int ws[16];
  __shared__ int hist_l[64];
  int t = threadIdx.x;
  if (t < 64) hist_l[t] = 0;
  __syncthreads();
  int carry = 0;
  for (int c = 0; c < 13; ++c) {
    int base = c * 4096 + t * 4;
    int degs[4], vals[4];
#pragma unroll
    for (int j = 0; j < 4; ++j) {
      degs[j] = (base + j < NN) ? cnt[base + j] : 0;
      vals[j] = (degs[j] + 7) & ~7;
      if (base + j >= NN) vals[j] = 0;
    }
    int tsum = vals[0] + vals[1] + vals[2] + vals[3];
    int lane = t & 63, wid = t >> 6;
    int x = tsum;
#pragma unroll
    for (int off = 1; off < 64; off <<= 1) {
      int y = __shfl_up(x, off, 64);
      if (lane >= off) x += y;
    }
    if (lane == 63) ws[wid] = x;
    __syncthreads();
    int woff = 0, total = 0;
#pragma unroll
    for (int w = 0; w < 16; ++w) {
      int v = ws[w];
      if (w < wid) woff += v;
      total += v;
    }
    int run = carry + woff + x - tsum;
#pragma unroll
    for (int j = 0; j < 4; ++j) {
      if (base + j < NN) {
        int deg = degs[j];
        row_ptr[base + j] = run;
        dinv[base + j] = rsqrtf(1.0f + (float)deg);
        int pd = vals[j];
        for (int p = deg; p < pd; ++p) col[run + p] = (unsigned short)NN;
        int it = pd >> 3;
        if (it > 63) it = 63;
        atomicAdd(&hist_l[63 - it], 1);  // descending bin (LPT)
        run += pd;
      }
    }
    carry += total;
    __syncthreads();  // protect ws reuse
  }
  if (t < 64) {
    int v = hist_l[t];
    int x = v;
#pragma unroll
    for (int off = 1; off < 64; off <<= 1) {
      int y = __shfl_up(x, off, 64);
      if (t >= off) x += y;
    }
    binoff[t] = x - v;  // exclusive scan of descending bins
  }
}

// ---------------- D4: CSR fill || degree-sorted order ---------------------
__global__ __launch_bounds__(256) void k_fillorder(
    const int* __restrict__ src, const int* __restrict__ dst,
    const int* __restrict__ row_ptr, int* __restrict__ cursor,
    unsigned short* __restrict__ col, const int* __restrict__ cnt,
    const float* __restrict__ dinv, const int* __restrict__ binoff,
    int* __restrict__ rank, int* __restrict__ order, i32x2* __restrict__ desc,
    float* __restrict__ dinvp) {
  int b = blockIdx.x, t = threadIdx.x;
  if (b < CNT_BLKS) {
    int i = b * 256 + t;
    if (i < NE) {
      int d = dst[i];
      int p = atomicAdd(&cursor[d], 1);
      col[row_ptr[d] + p] = (unsigned short)src[i];
    }
  } else {
    __shared__ int lcnt[64];
    __shared__ int gbase[64];
    if (t < 64) lcnt[t] = 0;
    __syncthreads();
    int i = (b - CNT_BLKS) * 256 + t;
    int bin = 0, rloc = 0, pd = 0;
    bool valid = (i < NN);
    if (valid) {
      pd = (cnt[i] + 7) & ~7;
      int it = pd >> 3;
      if (it > 63) it = 63;
      bin = 63 - it;
      rloc = atomicAdd(&lcnt[bin], 1);
    }
    __syncthreads();
    if (t < 64 && lcnt[t]) gbase[t] = binoff[t] + atomicAdd(&rank[t], lcnt[t]);
    __syncthreads();
    if (valid) {
      int p = gbase[bin] + rloc;
      order[p] = i;
      int rp = row_ptr[i];
      desc[p] = (i32x2){rp, rp + pd};
      dinvp[p] = dinv[i];
    }
  }
}

// ---------------- MFMA GEMM: 512 threads, half-W staged in LDS ------------
// Block = 8 waves x 16 rows = 128 rows, half = blockIdx.y (128 cols).
// W-half (64 KB) staged once per block -> W L2-traffic 8x lower than
// LDS-free; LDS 66 KB -> 2 blocks/CU = 16 waves/CU. bf16 activations
// (a_f32==0) in SUPERSLICE layout [4][NP][64]. BN finalize fused via stats.
__global__ __launch_bounds__(512) void k_mgemm(
    const void* __restrict__ Ap, int a_f32, const bf16_t* __restrict__ Wswz,
    bf16_t* __restrict__ Cb, float* __restrict__ Cf, int M,
    const float* __restrict__ stats, const float* __restrict__ gamma,
    const float* __restrict__ beta, const float* __restrict__ row_scale,
    const float* __restrict__ col_bias, int split) {
  __shared__ bf16_t Ws[64 * 512];  // 64 KB half-W
  __shared__ float bnsc_l[256], bnsh_l[256];
  const int tid = threadIdx.x;
  const int half = blockIdx.y;
  {
    const bf16_t* srcW = Wswz + (size_t)half * 64 * 512;
    bf16x8 wraw[8];
#pragma unroll
    for (int i = 0; i < 8; ++i)
      wraw[i] = *(const bf16x8*)&srcW[(i * 512 + tid) * 8];
#pragma unroll
    for (int i = 0; i < 8; ++i) *(bf16x8*)&Ws[(i * 512 + tid) * 8] = wraw[i];
  }
  if (stats && tid < 256) {
    float mean = stats[tid] * (1.0f / NN);
    float var = stats[256 + tid] * (1.0f / NN) - mean * mean;
    float rs = rsqrtf(var + BN_EPS);
    float sc = gamma[tid] * rs;
    bnsc_l[tid] = sc;
    bnsh_l[tid] = beta[tid] - mean * sc;
  }
  __syncthreads();

  const int wave = tid >> 6, lane = tid & 63;
  const int m = lane & 15, q = lane >> 4;  // A-frag: row m, k-octet q
  const int row0 = blockIdx.x * 128 + wave * 16;
  const int rg = row0 + m;
  const int rc = rg < M ? rg : M - 1;

  bf16x8 af[8];
  if (a_f32) {
    const float* p = (const float*)Ap + (size_t)rc * 256 + q * 8;
    float4 f0[8], f1[8];
#pragma unroll
    for (int kb = 0; kb < 8; ++kb) {
      f0[kb] = *(const float4*)(p + kb * 32);
      f1[kb] = *(const float4*)(p + kb * 32 + 4);
    }
#pragma unroll
    for (int kb = 0; kb < 8; ++kb) {
      bf16x8 fr;
      fr[0] = (bf16_t)f0[kb].x; fr[1] = (bf16_t)f0[kb].y;
      fr[2] = (bf16_t)f0[kb].z; fr[3] = (bf16_t)f0[kb].w;
      fr[4] = (bf16_t)f1[kb].x; fr[5] = (bf16_t)f1[kb].y;
      fr[6] = (bf16_t)f1[kb].z; fr[7] = (bf16_t)f1[kb].w;
      af[kb] = fr;
    }
  } else {
    const bf16_t* pA = (const bf16_t*)Ap;
    bf16x8 raw[8];
#pragma unroll
    for (int kb = 0; kb < 8; ++kb)
      raw[kb] = *(const bf16x8*)&pA[((size_t)(kb >> 1) * NP + rc) * 64 +
                                    (kb & 1) * 32 + q * 8];
#pragma unroll
    for (int kb = 0; kb < 8; ++kb) {
      float s[8], h[8];
      if (stats) {
        float4 s0 = *(const float4*)&bnsc_l[kb * 32 + q * 8];
        float4 s1 = *(const float4*)&bnsc_l[kb * 32 + q * 8 + 4];
        float4 h0 = *(const float4*)&bnsh_l[kb * 32 + q * 8];
        float4 h1 = *(const float4*)&bnsh_l[kb * 32 + q * 8 + 4];
        s[0] = s0.x; s[1] = s0.y; s[2] = s0.z; s[3] = s0.w;
        s[4] = s1.x; s[5] = s1.y; s[6] = s1.z; s[7] = s1.w;
        h[0] = h0.x; h[1] = h0.y; h[2] = h0.z; h[3] = h0.w;
        h[4] = h1.x; h[5] = h1.y; h[6] = h1.z; h[7] = h1.w;
      }
      bf16x8 r = raw[kb];
      bf16x8 fr;
#pragma unroll
      for (int j = 0; j < 8; ++j) {
        float v = (float)r[j];
        if (stats) v = fmaxf(fmaf(v, s[j], h[j]), 0.f);
        fr[j] = (bf16_t)v;
      }
      af[kb] = fr;
    }
  }

  f32x4 acc[8] = {};
#pragma unroll
  for (int nt = 0; nt < 8; ++nt) {
#pragma unroll
    for (int kb = 0; kb < 8; ++kb) {
      bf16x8 b = *(const bf16x8*)&Ws[(nt * 8 + kb) * 512 + lane * 8];
      acc[nt] =
          __builtin_amdgcn_mfma_f32_16x16x32_bf16(af[kb], b, acc[nt], 0, 0, 0);
    }
  }

  // epilogue: D row_local = q*4 + r, col_local = m  [m89-verified layout]
#pragma unroll
  for (int r = 0; r < 4; ++r) {
    int row = row0 + q * 4 + r;
    if (row >= M) continue;
    float rs = row_scale ? row_scale[row] : 1.0f;
#pragma unroll
    for (int nt = 0; nt < 8; ++nt) {
      int col = half * 128 + nt * 16 + m;
      float v = acc[nt][r] * rs;
      if (col_bias) v += col_bias[col];
      if (Cb) {
        Cb[((size_t)(col >> 6) * NP + row) * 64 + (col & 63)] = (bf16_t)v;
      } else if (!split) {
        Cf[(size_t)row * 256 + col] = v;
      } else {
        if (col < 128)
          Cf[(size_t)row * 128 + col] = v;
        else
          Cf[(size_t)(M + row) * 128 + (col - 128)] = v;
      }
    }
  }
}

// ---------------- SpMM + fused BN stats, XCD-pair superslices -------------
// g / out superslice-major [4][NP][64]. slice = blockIdx.x & 3. Teams of 8
// lanes (16 B/lane -> ONE 128 B line per gather), TWO degree-sorted rows
// per team (DESCENDING degree: heavy blocks first = LPT). col is u16.
#define ACCUM8(A, d)                                             \
  A[0] += (f32x2){__uint_as_float(d[0] << 16),                   \
                  __uint_as_float(d[0] & 0xffff0000u)};          \
  A[1] += (f32x2){__uint_as_float(d[1] << 16),                   \
                  __uint_as_float(d[1] & 0xffff0000u)};          \
  A[2] += (f32x2){__uint_as_float(d[2] << 16),                   \
                  __uint_as_float(d[2] & 0xffff0000u)};          \
  A[3] += (f32x2){__uint_as_float(d[3] << 16),                   \
                  __uint_as_float(d[3] & 0xffff0000u)};

__global__ __launch_bounds__(256) void k_spmm(
    const bf16_t* __restrict__ g, const int* __restrict__ order,
    const i32x2* __restrict__ desc, const unsigned short* __restrict__ col,
    const float* __restrict__ dinvp, bf16_t* __restrict__ out,
    float* __restrict__ stats) {
  __shared__ float sbuf[32][64];
  const int s = blockIdx.x & 3;
  const int grp = blockIdx.x >> 2;
  const int team = threadIdx.x >> 3, tl = threadIdx.x & 7;
  const int slotA = grp * 64 + team * 2;  // even; NN even -> A,B same validity
  const u32x4* gu = (const u32x4*)(g + (size_t)s * NP * 64);  // node*8 + tl
  float s1[8] = {}, s2[8] = {};
  if (slotA < NN) {
    f32x2 accA[4] = {}, accB[4] = {};
    i32x2 o2 = *(const i32x2*)&order[slotA];
    i32x4 d4 = *(const i32x4*)&desc[slotA];
    f32x2 dv2 = *(const f32x2*)&dinvp[slotA];
    int dstA = o2[0], dstB = o2[1];
    int bA = d4[0], eA = d4[1], bB = d4[2], eB = d4[3];
    {
      u32x4 dA = gu[(size_t)dstA * 8 + tl];
      u32x4 dB = gu[(size_t)dstB * 8 + tl];
      ACCUM8(accA, dA)
      ACCUM8(accB, dB)
    }
    u16x8 cA = {}, cB = {};
    if (bA < eA) cA = __builtin_nontemporal_load((const u16x8*)&col[bA]);
    if (bB < eB) cB = __builtin_nontemporal_load((const u16x8*)&col[bB]);
    while (bA < eA && bB < eB) {
      u32x4 wa0 = gu[(size_t)cA[0] * 8 + tl];
      u32x4 wa1 = gu[(size_t)cA[1] * 8 + tl];
      u32x4 wa2 = gu[(size_t)cA[2] * 8 + tl];
      u32x4 wa3 = gu[(size_t)cA[3] * 8 + tl];
      u32x4 wa4 = gu[(size_t)cA[4] * 8 + tl];
      u32x4 wa5 = gu[(size_t)cA[5] * 8 + tl];
      u32x4 wa6 = gu[(size_t)cA[6] * 8 + tl];
      u32x4 wa7 = gu[(size_t)cA[7] * 8 + tl];
      u32x4 wb0 = gu[(size_t)cB[0] * 8 + tl];
      u32x4 wb1 = gu[(size_t)cB[1] * 8 + tl];
      u32x4 wb2 = gu[(size_t)cB[2] * 8 + tl];
      u32x4 wb3 = gu[(size_t)cB[3] * 8 + tl];
      u32x4 wb4 = gu[(size_t)cB[4] * 8 + tl];
      u32x4 wb5 = gu[(size_t)cB[5] * 8 + tl];
      u32x4 wb6 = gu[(size_t)cB[6] * 8 + tl];
      u32x4 wb7 = gu[(size_t)cB[7] * 8 + tl];
      int bnA = bA + 8, bnB = bB + 8;
      u16x8 cnA = {}, cnB = {};
      if (bnA < eA) cnA = __builtin_nontemporal_load((const u16x8*)&col[bnA]);
      if (bnB < eB) cnB = __builtin_nontemporal_load((const u16x8*)&col[bnB]);
      ACCUM8(accA, wa0) ACCUM8(accA, wa1) ACCUM8(accA, wa2) ACCUM8(accA, wa3)
      ACCUM8(accA, wa4) ACCUM8(accA, wa5) ACCUM8(accA, wa6) ACCUM8(accA, wa7)
      ACCUM8(accB, wb0) ACCUM8(accB, wb1) ACCUM8(accB, wb2) ACCUM8(accB, wb3)
      ACCUM8(accB, wb4) ACCUM8(accB, wb5) ACCUM8(accB, wb6) ACCUM8(accB, wb7)
      cA = cnA;
      cB = cnB;
      bA = bnA;
      bB = bnB;
    }
    while (bA < eA) {  // A tail
      u32x4 w0 = gu[(size_t)cA[0] * 8 + tl];
      u32x4 w1 = gu[(size_t)cA[1] * 8 + tl];
      u32x4 w2 = gu[(size_t)cA[2] * 8 + tl];
      u32x4 w3 = gu[(size_t)cA[3] * 8 + tl];
      u32x4 w4 = gu[(size_t)cA[4] * 8 + tl];
      u32x4 w5 = gu[(size_t)cA[5] * 8 + tl];
      u32x4 w6 = gu[(size_t)cA[6] * 8 + tl];
      u32x4 w7 = gu[(size_t)cA[7] * 8 + tl];
      int bn = bA + 8;
      u16x8 cn = {};
      if (bn < eA) cn = __builtin_nontemporal_load((const u16x8*)&col[bn]);
      ACCUM8(accA, w0) ACCUM8(accA, w1) ACCUM8(accA, w2) ACCUM8(accA, w3)
      ACCUM8(accA, w4) ACCUM8(accA, w5) ACCUM8(accA, w6) ACCUM8(accA, w7)
      cA = cn;
      bA = bn;
    }
    while (bB < eB) {  // B tail
      u32x4 w0 = gu[(size_t)cB[0] * 8 + tl];
      u32x4 w1 = gu[(size_t)cB[1] * 8 + tl];
      u32x4 w2 = gu[(size_t)cB[2] * 8 + tl];
      u32x4 w3 = gu[(size_t)cB[3] * 8 + tl];
      u32x4 w4 = gu[(size_t)cB[4] * 8 + tl];
      u32x4 w5 = gu[(size_t)cB[5] * 8 + tl];
      u32x4 w6 = gu[(size_t)cB[6] * 8 + tl];
      u32x4 w7 = gu[(size_t)cB[7] * 8 + tl];
      int bn = bB + 8;
      u16x8 cn = {};
      if (bn < eB) cn = __builtin_nontemporal_load((const u16x8*)&col[bn]);
      ACCUM8(accB, w0) ACCUM8(accB, w1) ACCUM8(accB, w2) ACCUM8(accB, w3)
      ACCUM8(accB, w4) ACCUM8(accB, w5) ACCUM8(accB, w6) ACCUM8(accB, w7)
      cB = cn;
      bB = bn;
    }
    float dvA = dv2[0], dvB = dv2[1];
    bf16x8 ovA, ovB;
#pragma unroll
    for (int j = 0; j < 8; ++j) {
      ovA[j] = (bf16_t)(accA[j >> 1][j & 1] * dvA);
      ovB[j] = (bf16_t)(accB[j >> 1][j & 1] * dvB);
    }
    __builtin_nontemporal_store(
        ovA, (bf16x8*)&out[((size_t)s * NP + dstA) * 64 + (size_t)tl * 8]);
    __builtin_nontemporal_store(
        ovB, (bf16x8*)&out[((size_t)s * NP + dstB) * 64 + (size_t)tl * 8]);
#pragma unroll
    for (int j = 0; j < 8; ++j) {
      float va = (float)ovA[j], vb = (float)ovB[j];
      s1[j] += va + vb;
      s2[j] = fmaf(va, va, s2[j]);
      s2[j] = fmaf(vb, vb, s2[j]);
    }
  }
  // block reduction of stats (64 feats of this slice across 32 teams)
#pragma unroll
  for (int j = 0; j < 8; ++j) sbuf[team][tl * 8 + j] = s1[j];
  __syncthreads();
  if (threadIdx.x < 64) {
    float tot = 0.f;
#pragma unroll
    for (int w = 0; w < 32; ++w) tot += sbuf[w][threadIdx.x];
    atomicAdd(&stats[s * 64 + threadIdx.x], tot);
  }
  __syncthreads();
#pragma unroll
  for (int j = 0; j < 8; ++j) sbuf[team][tl * 8 + j] = s2[j];
  __syncthreads();
  if (threadIdx.x < 64) {
    float tot = 0.f;
#pragma unroll
    for (int w = 0; w < 32; ++w) tot += sbuf[w][threadIdx.x];
    atomicAdd(&stats[256 + s * 64 + threadIdx.x], tot);
  }
}

// ---------------- launch ----------------
extern "C" void kernel_launch(void* const* d_in, const int* in_sizes, int n_in,
                              void* d_out, int out_size, void* d_ws, size_t ws_size,
                              hipStream_t stream) {
  const float* x = (const float*)d_in[0];
  const int* ei = (const int*)d_in[1];
  const int* esrc = ei;
  const int* edst = ei + NE;
  const float* W0 = (const float*)d_in[2];
  const float* gamma0 = (const float*)d_in[4];
  const float* beta0 = (const float*)d_in[5];
  const float* W1 = (const float*)d_in[6];
  const float* gamma1 = (const float*)d_in[8];
  const float* beta1 = (const float*)d_in[9];
  const float* W_mu = (const float*)d_in[10];
  const float* b_mu = (const float*)d_in[11];
  const float* W_lv = (const float*)d_in[12];
  const float* b_lv = (const float*)d_in[13];
  float* out = (float*)d_out;

  // workspace carve: cnt|cursor|statsAll|hist|rank contiguous -> one memset
  bf16_t* g16 = (bf16_t*)d_ws;                        // 4*NP*64 (superslice)
  bf16_t* agg16 = g16 + (size_t)4 * NP * 64;          // 4*NP*64 (superslice)
  int* cnt = (int*)(agg16 + (size_t)4 * NP * 64);     // NN
  int* cursor = cnt + NN;                             // NN
  float* statsAll = (float*)(cursor + NN);            // 1024 (2 layers x 512)
  int* hist = (int*)(statsAll + 1024);                // 64 (unused, kept)
  int* rank = hist + 64;                              // 64
  float* dinv = (float*)(rank + 64);                  // NN
  float* biash = dinv + NN;                           // 256
  bf16_t* W0s = (bf16_t*)(biash + 256);               // 65536 each
  bf16_t* W1s = W0s + 256 * 256;
  bf16_t* Whs = W1s + 256 * 256;
  int* row_ptr = (int*)(Whs + 256 * 256);             // NN+4
  int* order = row_ptr + NN + 4;                      // NN
  float* dinvp = (float*)(order + NN);                // NN
  i32x2* desc = (i32x2*)(dinvp + NN);                 // NN (8 B each)
  unsigned short* col = (unsigned short*)(desc + NN); // NEPAD u16 (16B align)
  int* binoff = (int*)(col + NEPAD);                  // 64

  hipMemsetAsync(cnt, 0, (2 * NN + 1024 + 128) * sizeof(int), stream);
  k_countw<<<CNT_BLKS + 256, 256, 0, stream>>>(edst, cnt, W0, W1, W_mu, b_mu,
                                               W_lv, b_lv, W0s, W1s, Whs,
                                               biash, g16, agg16);
  k_scan<<<1, 1024, 0, stream>>>(cnt, row_ptr, dinv, col, binoff);
  k_fillorder<<<CNT_BLKS + ORD_BLKS, 256, 0, stream>>>(
      esrc, edst, row_ptr, cursor, col, cnt, dinv, binoff, rank, order, desc,
      dinvp);

  dim3 gg((NN + 127) / 128, 2);  // 391 x 2, 512 threads, 128 rows/block
  const int SPMM_BLKS = 4 * ((NN + 63) / 64);  // 3128, slice = bid & 3

  // layer 0
  k_mgemm<<<gg, 512, 0, stream>>>(x, 1, W0s, g16, nullptr, NN, nullptr, nullptr,
                                  nullptr, dinv, nullptr, 0);
  k_spmm<<<SPMM_BLKS, 256, 0, stream>>>(g16, order, desc, col, dinvp, agg16,
                                        statsAll);

  // layer 1 (BN finalize of layer 0 fused into mgemm)
  k_mgemm<<<gg, 512, 0, stream>>>(agg16, 0, W1s, g16, nullptr, NN, statsAll,
                                  gamma0, beta0, dinv, nullptr, 0);
  k_spmm<<<SPMM_BLKS, 256, 0, stream>>>(g16, order, desc, col, dinvp, agg16,
                                        statsAll + 512);

  // heads (fused mu|logvar; BN finalize of layer 1 fused)
  k_mgemm<<<gg, 512, 0, stream>>>(agg16, 0, Whs, nullptr, out, NN,
                                  statsAll + 512, gamma1, beta1, nullptr, biash,
                                  1);
}

// Round 11
// 373.969 us; speedup vs baseline: 1.4802x; 1.2265x over previous
//
#include <hip/hip_runtime.h>
#include <hip/hip_bf16.h>

#define NN 50000
#define NP 50001  // row stride incl. zero-row at index NN
#define NE 800000
#define FD 256
#define LD 128
#define BN_EPS 1e-5f
#define NEPAD (NE + 7 * NN + 16)
#define CNT_BLKS 3125   // NE/256
#define ORD_BLKS 196    // ceil(NN/256)
#define SCAN_BLKS 49    // ceil(NN/1024)

typedef __bf16 bf16_t;
typedef bf16_t bf16x8 __attribute__((ext_vector_type(8)));
typedef float f32x4 __attribute__((ext_vector_type(4)));
typedef float f32x2 __attribute__((ext_vector_type(2)));
typedef int i32x2 __attribute__((ext_vector_type(2)));
typedef int i32x4 __attribute__((ext_vector_type(4)));
typedef unsigned int u32x4 __attribute__((ext_vector_type(4)));
typedef unsigned short u16x8 __attribute__((ext_vector_type(8)));

// ---------------- D2: degree count || weight swizzle ----------------------
__global__ __launch_bounds__(256) void k_countw(
    const int* __restrict__ dst, int* __restrict__ cnt,
    const float* __restrict__ W0, const float* __restrict__ W1,
    const float* __restrict__ Wmu, const float* __restrict__ bmu,
    const float* __restrict__ Wlv, const float* __restrict__ blv,
    bf16_t* __restrict__ W0s, bf16_t* __restrict__ W1s,
    bf16_t* __restrict__ Whs, float* __restrict__ biash,
    bf16_t* __restrict__ g16, bf16_t* __restrict__ agg16) {
  int b = blockIdx.x, t = threadIdx.x;
  if (b < CNT_BLKS) {
    int i = b * 256 + t;
    if (i < NE) atomicAdd(&cnt[dst[i]], 1);
  } else {
    int k = b - CNT_BLKS, n = t;
    int chunk = (n >> 4) * 8 + (k >> 5);
    int slot = ((k >> 3) & 3) * 16 + (n & 15);
    int idx = chunk * 512 + slot * 8 + (k & 7);
    W0s[idx] = (bf16_t)W0[k * 256 + n];
    W1s[idx] = (bf16_t)W1[k * 256 + n];
    float wh = (n < 128) ? Wmu[k * 128 + n] : Wlv[k * 128 + (n - 128)];
    Whs[idx] = (bf16_t)wh;
    if (k == 0) biash[n] = (n < 128) ? bmu[n] : blv[n - 128];
    if (k == 1) {
      int ss = n >> 6, j = n & 63;
      g16[((size_t)ss * NP + NN) * 64 + j] = (bf16_t)0.f;
      agg16[((size_t)ss * NP + NN) * 64 + j] = (bf16_t)0.f;
    }
  }
}

// ---------------- D3: block-level padded scan + dinv ----------------------
__global__ __launch_bounds__(256) void k_scanA(const int* __restrict__ cnt,
                                               int* __restrict__ row_ptr,
                                               int* __restrict__ partials,
                                               float* __restrict__ dinv) {
  __shared__ int ws[4];
  int b = blockIdx.x, t = threadIdx.x;
  int base = b * 1024 + t * 4;
  int vals[4];
#pragma unroll
  for (int j = 0; j < 4; ++j) {
    int deg = (base + j < NN) ? cnt[base + j] : 0;
    vals[j] = (base + j < NN) ? ((deg + 7) & ~7) : 0;
    if (base + j < NN) dinv[base + j] = rsqrtf(1.0f + (float)deg);
  }
  int tsum = vals[0] + vals[1] + vals[2] + vals[3];
  int lane = t & 63, wid = t >> 6;
  int x = tsum;
#pragma unroll
  for (int off = 1; off < 64; off <<= 1) {
    int y = __shfl_up(x, off, 64);
    if (lane >= off) x += y;
  }
  if (lane == 63) ws[wid] = x;
  __syncthreads();
  int woff = 0;
  for (int w = 0; w < wid; ++w) woff += ws[w];
  int run = woff + x - tsum;
#pragma unroll
  for (int j = 0; j < 4; ++j) {
    if (base + j < NN) row_ptr[base + j] = run;
    run += vals[j];
  }
  if (t == 255) partials[b] = woff + x;
}

__global__ void k_scanB(int* __restrict__ partials, int* __restrict__ row_ptr) {
  int lane = threadIdx.x;
  int v = (lane < SCAN_BLKS) ? partials[lane] : 0;
  int x = v;
#pragma unroll
  for (int off = 1; off < 64; off <<= 1) {
    int y = __shfl_up(x, off, 64);
    if (lane >= off) x += y;
  }
  if (lane < SCAN_BLKS) partials[lane] = x - v;
  if (lane == SCAN_BLKS - 1) row_ptr[NN] = x;
}

// scanC: finalize row_ptr, pad col slots, descending-degree histogram (LPT)
__global__ __launch_bounds__(256) void k_scanC(int* __restrict__ row_ptr,
                                               const int* __restrict__ partials,
                                               const int* __restrict__ cnt,
                                               unsigned short* __restrict__ col,
                                               int* __restrict__ hist) {
  __shared__ int lh[64];
  int b = blockIdx.x, t = threadIdx.x;
  if (t < 64) lh[t] = 0;
  __syncthreads();
  int off = partials[b];
  int base = b * 1024 + t * 4;
#pragma unroll
  for (int j = 0; j < 4; ++j)
    if (base + j < NN) {
      int deg = cnt[base + j];
      int rp = row_ptr[base + j] + off;
      row_ptr[base + j] = rp;
      int pd = (deg + 7) & ~7;
      for (int p = deg; p < pd; ++p) col[rp + p] = (unsigned short)NN;
      int it = pd >> 3;
      if (it > 63) it = 63;
      atomicAdd(&lh[63 - it], 1);  // descending bin (LPT)
    }
  __syncthreads();
  if (t < 64 && lh[t]) atomicAdd(&hist[t], lh[t]);
}

// ---------------- D4: CSR fill || degree-sorted order ---------------------
// order blocks re-derive binoff from hist via an in-wave exclusive scan.
__global__ __launch_bounds__(256) void k_fillorder(
    const int* __restrict__ src, const int* __restrict__ dst,
    const int* __restrict__ row_ptr, int* __restrict__ cursor,
    unsigned short* __restrict__ col, const int* __restrict__ cnt,
    const float* __restrict__ dinv, const int* __restrict__ hist,
    int* __restrict__ rank, int* __restrict__ order, i32x2* __restrict__ desc,
    float* __restrict__ dinvp) {
  int b = blockIdx.x, t = threadIdx.x;
  if (b < CNT_BLKS) {
    int i = b * 256 + t;
    if (i < NE) {
      int d = dst[i];
      int p = atomicAdd(&cursor[d], 1);
      col[row_ptr[d] + p] = (unsigned short)src[i];
    }
  } else {
    __shared__ int lcnt[64];
    __shared__ int gbase[64];
    __shared__ int sc[64];
    if (t < 64) {
      lcnt[t] = 0;
      int v = hist[t];
      int x = v;
#pragma unroll
      for (int off = 1; off < 64; off <<= 1) {
        int y = __shfl_up(x, off, 64);
        if (t >= off) x += y;
      }
      sc[t] = x - v;  // exclusive scan of descending bins
    }
    __syncthreads();
    int i = (b - CNT_BLKS) * 256 + t;
    int bin = 0, rloc = 0, pd = 0;
    bool valid = (i < NN);
    if (valid) {
      pd = (cnt[i] + 7) & ~7;
      int it = pd >> 3;
      if (it > 63) it = 63;
      bin = 63 - it;
      rloc = atomicAdd(&lcnt[bin], 1);
    }
    __syncthreads();
    if (t < 64 && lcnt[t]) gbase[t] = sc[t] + atomicAdd(&rank[t], lcnt[t]);
    __syncthreads();
    if (valid) {
      int p = gbase[bin] + rloc;
      order[p] = i;
      int rp = row_ptr[i];
      desc[p] = (i32x2){rp, rp + pd};
      dinvp[p] = dinv[i];
    }
  }
}

// ---------------- MFMA GEMM: 512 threads, half-W staged in LDS ------------
// Block = 8 waves x 16 rows = 128 rows, half = blockIdx.y (128 cols).
// W-half (64 KB) staged once per block; LDS 66 KB -> 2 blocks/CU = 16
// waves/CU. bf16 activations (a_f32==0) in SUPERSLICE layout [4][NP][64].
// BN finalize fused via stats.
__global__ __launch_bounds__(512) void k_mgemm(
    const void* __restrict__ Ap, int a_f32, const bf16_t* __restrict__ Wswz,
    bf16_t* __restrict__ Cb, float* __restrict__ Cf, int M,
    const float* __restrict__ stats, const float* __restrict__ gamma,
    const float* __restrict__ beta, const float* __restrict__ row_scale,
    const float* __restrict__ col_bias, int split) {
  __shared__ bf16_t Ws[64 * 512];  // 64 KB half-W
  __shared__ float bnsc_l[256], bnsh_l[256];
  const int tid = threadIdx.x;
  const int half = blockIdx.y;
  {
    const bf16_t* srcW = Wswz + (size_t)half * 64 * 512;
    bf16x8 wraw[8];
#pragma unroll
    for (int i = 0; i < 8; ++i)
      wraw[i] = *(const bf16x8*)&srcW[(i * 512 + tid) * 8];
#pragma unroll
    for (int i = 0; i < 8; ++i) *(bf16x8*)&Ws[(i * 512 + tid) * 8] = wraw[i];
  }
  if (stats && tid < 256) {
    float mean = stats[tid] * (1.0f / NN);
    float var = stats[256 + tid] * (1.0f / NN) - mean * mean;
    float rs = rsqrtf(var + BN_EPS);
    float sc = gamma[tid] * rs;
    bnsc_l[tid] = sc;
    bnsh_l[tid] = beta[tid] - mean * sc;
  }
  __syncthreads();

  const int wave = tid >> 6, lane = tid & 63;
  const int m = lane & 15, q = lane >> 4;  // A-frag: row m, k-octet q
  const int row0 = blockIdx.x * 128 + wave * 16;
  const int rg = row0 + m;
  const int rc = rg < M ? rg : M - 1;

  bf16x8 af[8];
  if (a_f32) {
    const float* p = (const float*)Ap + (size_t)rc * 256 + q * 8;
    float4 f0[8], f1[8];
#pragma unroll
    for (int kb = 0; kb < 8; ++kb) {
      f0[kb] = *(const float4*)(p + kb * 32);
      f1[kb] = *(const float4*)(p + kb * 32 + 4);
    }
#pragma unroll
    for (int kb = 0; kb < 8; ++kb) {
      bf16x8 fr;
      fr[0] = (bf16_t)f0[kb].x; fr[1] = (bf16_t)f0[kb].y;
      fr[2] = (bf16_t)f0[kb].z; fr[3] = (bf16_t)f0[kb].w;
      fr[4] = (bf16_t)f1[kb].x; fr[5] = (bf16_t)f1[kb].y;
      fr[6] = (bf16_t)f1[kb].z; fr[7] = (bf16_t)f1[kb].w;
      af[kb] = fr;
    }
  } else {
    const bf16_t* pA = (const bf16_t*)Ap;
    bf16x8 raw[8];
#pragma unroll
    for (int kb = 0; kb < 8; ++kb)
      raw[kb] = *(const bf16x8*)&pA[((size_t)(kb >> 1) * NP + rc) * 64 +
                                    (kb & 1) * 32 + q * 8];
#pragma unroll
    for (int kb = 0; kb < 8; ++kb) {
      float s[8], h[8];
      if (stats) {
        float4 s0 = *(const float4*)&bnsc_l[kb * 32 + q * 8];
        float4 s1 = *(const float4*)&bnsc_l[kb * 32 + q * 8 + 4];
        float4 h0 = *(const float4*)&bnsh_l[kb * 32 + q * 8];
        float4 h1 = *(const float4*)&bnsh_l[kb * 32 + q * 8 + 4];
        s[0] = s0.x; s[1] = s0.y; s[2] = s0.z; s[3] = s0.w;
        s[4] = s1.x; s[5] = s1.y; s[6] = s1.z; s[7] = s1.w;
        h[0] = h0.x; h[1] = h0.y; h[2] = h0.z; h[3] = h0.w;
        h[4] = h1.x; h[5] = h1.y; h[6] = h1.z; h[7] = h1.w;
      }
      bf16x8 r = raw[kb];
      bf16x8 fr;
#pragma unroll
      for (int j = 0; j < 8; ++j) {
        float v = (float)r[j];
        if (stats) v = fmaxf(fmaf(v, s[j], h[j]), 0.f);
        fr[j] = (bf16_t)v;
      }
      af[kb] = fr;
    }
  }

  f32x4 acc[8] = {};
#pragma unroll
  for (int nt = 0; nt < 8; ++nt) {
#pragma unroll
    for (int kb = 0; kb < 8; ++kb) {
      bf16x8 b = *(const bf16x8*)&Ws[(nt * 8 + kb) * 512 + lane * 8];
      acc[nt] =
          __builtin_amdgcn_mfma_f32_16x16x32_bf16(af[kb], b, acc[nt], 0, 0, 0);
    }
  }

  // epilogue: D row_local = q*4 + r, col_local = m  [m89-verified layout]
#pragma unroll
  for (int r = 0; r < 4; ++r) {
    int row = row0 + q * 4 + r;
    if (row >= M) continue;
    float rs = row_scale ? row_scale[row] : 1.0f;
#pragma unroll
    for (int nt = 0; nt < 8; ++nt) {
      int col = half * 128 + nt * 16 + m;
      float v = acc[nt][r] * rs;
      if (col_bias) v += col_bias[col];
      if (Cb) {
        Cb[((size_t)(col >> 6) * NP + row) * 64 + (col & 63)] = (bf16_t)v;
      } else if (!split) {
        Cf[(size_t)row * 256 + col] = v;
      } else {
        if (col < 128)
          Cf[(size_t)row * 128 + col] = v;
        else
          Cf[(size_t)(M + row) * 128 + (col - 128)] = v;
      }
    }
  }
}

// ---------------- SpMM + fused BN stats, XCD-pair superslices -------------
// g / out superslice-major [4][NP][64]. slice = blockIdx.x & 3. Teams of 8
// lanes (16 B/lane -> ONE 128 B line per gather), TWO degree-sorted rows
// per team (DESCENDING degree: heavy blocks first = LPT). col is u16.
#define ACCUM8(A, d)                                             \
  A[0] += (f32x2){__uint_as_float(d[0] << 16),                   \
                  __uint_as_float(d[0] & 0xffff0000u)};          \
  A[1] += (f32x2){__uint_as_float(d[1] << 16),                   \
                  __uint_as_float(d[1] & 0xffff0000u)};          \
  A[2] += (f32x2){__uint_as_float(d[2] << 16),                   \
                  __uint_as_float(d[2] & 0xffff0000u)};          \
  A[3] += (f32x2){__uint_as_float(d[3] << 16),                   \
                  __uint_as_float(d[3] & 0xffff0000u)};

__global__ __launch_bounds__(256) void k_spmm(
    const bf16_t* __restrict__ g, const int* __restrict__ order,
    const i32x2* __restrict__ desc, const unsigned short* __restrict__ col,
    const float* __restrict__ dinvp, bf16_t* __restrict__ out,
    float* __restrict__ stats) {
  __shared__ float sbuf[32][64];
  const int s = blockIdx.x & 3;
  const int grp = blockIdx.x >> 2;
  const int team = threadIdx.x >> 3, tl = threadIdx.x & 7;
  const int slotA = grp * 64 + team * 2;  // even; NN even -> A,B same validity
  const u32x4* gu = (const u32x4*)(g + (size_t)s * NP * 64);  // node*8 + tl
  float s1[8] = {}, s2[8] = {};
  if (slotA < NN) {
    f32x2 accA[4] = {}, accB[4] = {};
    i32x2 o2 = *(const i32x2*)&order[slotA];
    i32x4 d4 = *(const i32x4*)&desc[slotA];
    f32x2 dv2 = *(const f32x2*)&dinvp[slotA];
    int dstA = o2[0], dstB = o2[1];
    int bA = d4[0], eA = d4[1], bB = d4[2], eB = d4[3];
    {
      u32x4 dA = gu[(size_t)dstA * 8 + tl];
      u32x4 dB = gu[(size_t)dstB * 8 + tl];
      ACCUM8(accA, dA)
      ACCUM8(accB, dB)
    }
    u16x8 cA = {}, cB = {};
    if (bA < eA) cA = __builtin_nontemporal_load((const u16x8*)&col[bA]);
    if (bB < eB) cB = __builtin_nontemporal_load((const u16x8*)&col[bB]);
    while (bA < eA && bB < eB) {
      u32x4 wa0 = gu[(size_t)cA[0] * 8 + tl];
      u32x4 wa1 = gu[(size_t)cA[1] * 8 + tl];
      u32x4 wa2 = gu[(size_t)cA[2] * 8 + tl];
      u32x4 wa3 = gu[(size_t)cA[3] * 8 + tl];
      u32x4 wa4 = gu[(size_t)cA[4] * 8 + tl];
      u32x4 wa5 = gu[(size_t)cA[5] * 8 + tl];
      u32x4 wa6 = gu[(size_t)cA[6] * 8 + tl];
      u32x4 wa7 = gu[(size_t)cA[7] * 8 + tl];
      u32x4 wb0 = gu[(size_t)cB[0] * 8 + tl];
      u32x4 wb1 = gu[(size_t)cB[1] * 8 + tl];
      u32x4 wb2 = gu[(size_t)cB[2] * 8 + tl];
      u32x4 wb3 = gu[(size_t)cB[3] * 8 + tl];
      u32x4 wb4 = gu[(size_t)cB[4] * 8 + tl];
      u32x4 wb5 = gu[(size_t)cB[5] * 8 + tl];
      u32x4 wb6 = gu[(size_t)cB[6] * 8 + tl];
      u32x4 wb7 = gu[(size_t)cB[7] * 8 + tl];
      int bnA = bA + 8, bnB = bB + 8;
      u16x8 cnA = {}, cnB = {};
      if (bnA < eA) cnA = __builtin_nontemporal_load((const u16x8*)&col[bnA]);
      if (bnB < eB) cnB = __builtin_nontemporal_load((const u16x8*)&col[bnB]);
      ACCUM8(accA, wa0) ACCUM8(accA, wa1) ACCUM8(accA, wa2) ACCUM8(accA, wa3)
      ACCUM8(accA, wa4) ACCUM8(accA, wa5) ACCUM8(accA, wa6) ACCUM8(accA, wa7)
      ACCUM8(accB, wb0) ACCUM8(accB, wb1) ACCUM8(accB, wb2) ACCUM8(accB, wb3)
      ACCUM8(accB, wb4) ACCUM8(accB, wb5) ACCUM8(accB, wb6) ACCUM8(accB, wb7)
      cA = cnA;
      cB = cnB;
      bA = bnA;
      bB = bnB;
    }
    while (bA < eA) {  // A tail
      u32x4 w0 = gu[(size_t)cA[0] * 8 + tl];
      u32x4 w1 = gu[(size_t)cA[1] * 8 + tl];
      u32x4 w2 = gu[(size_t)cA[2] * 8 + tl];
      u32x4 w3 = gu[(size_t)cA[3] * 8 + tl];
      u32x4 w4 = gu[(size_t)cA[4] * 8 + tl];
      u32x4 w5 = gu[(size_t)cA[5] * 8 + tl];
      u32x4 w6 = gu[(size_t)cA[6] * 8 + tl];
      u32x4 w7 = gu[(size_t)cA[7] * 8 + tl];
      int bn = bA + 8;
      u16x8 cn = {};
      if (bn < eA) cn = __builtin_nontemporal_load((const u16x8*)&col[bn]);
      ACCUM8(accA, w0) ACCUM8(accA, w1) ACCUM8(accA, w2) ACCUM8(accA, w3)
      ACCUM8(accA, w4) ACCUM8(accA, w5) ACCUM8(accA, w6) ACCUM8(accA, w7)
      cA = cn;
      bA = bn;
    }
    while (bB < eB) {  // B tail
      u32x4 w0 = gu[(size_t)cB[0] * 8 + tl];
      u32x4 w1 = gu[(size_t)cB[1] * 8 + tl];
      u32x4 w2 = gu[(size_t)cB[2] * 8 + tl];
      u32x4 w3 = gu[(size_t)cB[3] * 8 + tl];
      u32x4 w4 = gu[(size_t)cB[4] * 8 + tl];
      u32x4 w5 = gu[(size_t)cB[5] * 8 + tl];
      u32x4 w6 = gu[(size_t)cB[6] * 8 + tl];
      u32x4 w7 = gu[(size_t)cB[7] * 8 + tl];
      int bn = bB + 8;
      u16x8 cn = {};
      if (bn < eB) cn = __builtin_nontemporal_load((const u16x8*)&col[bn]);
      ACCUM8(accB, w0) ACCUM8(accB, w1) ACCUM8(accB, w2) ACCUM8(accB, w3)
      ACCUM8(accB, w4) ACCUM8(accB, w5) ACCUM8(accB, w6) ACCUM8(accB, w7)
      cB = cn;
      bB = bn;
    }
    float dvA = dv2[0], dvB = dv2[1];
    bf16x8 ovA, ovB;
#pragma unroll
    for (int j = 0; j < 8; ++j) {
      ovA[j] = (bf16_t)(accA[j >> 1][j & 1] * dvA);
      ovB[j] = (bf16_t)(accB[j >> 1][j & 1] * dvB);
    }
    __builtin_nontemporal_store(
        ovA, (bf16x8*)&out[((size_t)s * NP + dstA) * 64 + (size_t)tl * 8]);
    __builtin_nontemporal_store(
        ovB, (bf16x8*)&out[((size_t)s * NP + dstB) * 64 + (size_t)tl * 8]);
#pragma unroll
    for (int j = 0; j < 8; ++j) {
      float va = (float)ovA[j], vb = (float)ovB[j];
      s1[j] += va + vb;
      s2[j] = fmaf(va, va, s2[j]);
      s2[j] = fmaf(vb, vb, s2[j]);
    }
  }
  // block reduction of stats (64 feats of this slice across 32 teams)
#pragma unroll
  for (int j = 0; j < 8; ++j) sbuf[team][tl * 8 + j] = s1[j];
  __syncthreads();
  if (threadIdx.x < 64) {
    float tot = 0.f;
#pragma unroll
    for (int w = 0; w < 32; ++w) tot += sbuf[w][threadIdx.x];
    atomicAdd(&stats[s * 64 + threadIdx.x], tot);
  }
  __syncthreads();
#pragma unroll
  for (int j = 0; j < 8; ++j) sbuf[team][tl * 8 + j] = s2[j];
  __syncthreads();
  if (threadIdx.x < 64) {
    float tot = 0.f;
#pragma unroll
    for (int w = 0; w < 32; ++w) tot += sbuf[w][threadIdx.x];
    atomicAdd(&stats[256 + s * 64 + threadIdx.x], tot);
  }
}

// ---------------- launch ----------------
extern "C" void kernel_launch(void* const* d_in, const int* in_sizes, int n_in,
                              void* d_out, int out_size, void* d_ws, size_t ws_size,
                              hipStream_t stream) {
  const float* x = (const float*)d_in[0];
  const int* ei = (const int*)d_in[1];
  const int* esrc = ei;
  const int* edst = ei + NE;
  const float* W0 = (const float*)d_in[2];
  const float* gamma0 = (const float*)d_in[4];
  const float* beta0 = (const float*)d_in[5];
  const float* W1 = (const float*)d_in[6];
  const float* gamma1 = (const float*)d_in[8];
  const float* beta1 = (const float*)d_in[9];
  const float* W_mu = (const float*)d_in[10];
  const float* b_mu = (const float*)d_in[11];
  const float* W_lv = (const float*)d_in[12];
  const float* b_lv = (const float*)d_in[13];
  float* out = (float*)d_out;

  // workspace carve: cnt|cursor|statsAll|hist|rank contiguous -> one memset
  bf16_t* g16 = (bf16_t*)d_ws;                        // 4*NP*64 (superslice)
  bf16_t* agg16 = g16 + (size_t)4 * NP * 64;          // 4*NP*64 (superslice)
  int* cnt = (int*)(agg16 + (size_t)4 * NP * 64);     // NN
  int* cursor = cnt + NN;                             // NN
  float* statsAll = (float*)(cursor + NN);            // 1024 (2 layers x 512)
  int* hist = (int*)(statsAll + 1024);                // 64
  int* rank = hist + 64;                              // 64
  float* dinv = (float*)(rank + 64);                  // NN
  float* biash = dinv + NN;                           // 256
  bf16_t* W0s = (bf16_t*)(biash + 256);               // 65536 each
  bf16_t* W1s = W0s + 256 * 256;
  bf16_t* Whs = W1s + 256 * 256;
  int* row_ptr = (int*)(Whs + 256 * 256);             // NN+4
  int* order = row_ptr + NN + 4;                      // NN
  float* dinvp = (float*)(order + NN);                // NN
  i32x2* desc = (i32x2*)(dinvp + NN);                 // NN (8 B each)
  unsigned short* col = (unsigned short*)(desc + NN); // NEPAD u16 (16B align)
  int* partials = (int*)(col + NEPAD);                // 64

  hipMemsetAsync(cnt, 0, (2 * NN + 1024 + 128) * sizeof(int), stream);
  k_countw<<<CNT_BLKS + 256, 256, 0, stream>>>(edst, cnt, W0, W1, W_mu, b_mu,
                                               W_lv, b_lv, W0s, W1s, Whs,
                                               biash, g16, agg16);
  k_scanA<<<SCAN_BLKS, 256, 0, stream>>>(cnt, row_ptr, partials, dinv);
  k_scanB<<<1, 64, 0, stream>>>(partials, row_ptr);
  k_scanC<<<SCAN_BLKS, 256, 0, stream>>>(row_ptr, partials, cnt, col, hist);
  k_fillorder<<<CNT_BLKS + ORD_BLKS, 256, 0, stream>>>(
      esrc, edst, row_ptr, cursor, col, cnt, dinv, hist, rank, order, desc,
      dinvp);

  dim3 gg((NN + 127) / 128, 2);  // 391 x 2, 512 threads, 128 rows/block
  const int SPMM_BLKS = 4 * ((NN + 63) / 64);  // 3128, slice = bid & 3

  // layer 0
  k_mgemm<<<gg, 512, 0, stream>>>(x, 1, W0s, g16, nullptr, NN, nullptr, nullptr,
                                  nullptr, dinv, nullptr, 0);
  k_spmm<<<SPMM_BLKS, 256, 0, stream>>>(g16, order, desc, col, dinvp, agg16,
                                        statsAll);

  // layer 1 (BN finalize of layer 0 fused into mgemm)
  k_mgemm<<<gg, 512, 0, stream>>>(agg16, 0, W1s, g16, nullptr, NN, statsAll,
                                  gamma0, beta0, dinv, nullptr, 0);
  k_spmm<<<SPMM_BLKS, 256, 0, stream>>>(g16, order, desc, col, dinvp, agg16,
                                        statsAll + 512);

  // heads (fused mu|logvar; BN finalize of layer 1 fused)
  k_mgemm<<<gg, 512, 0, stream>>>(agg16, 0, Whs, nullptr, out, NN,
                                  statsAll + 512, gamma1, beta1, nullptr, biash,
                                  1);
}

// Round 12
// 350.708 us; speedup vs baseline: 1.5784x; 1.0663x over previous
//
#include <hip/hip_runtime.h>
#include <hip/hip_bf16.h>

#define NN 50000
#define NP 50001  // row stride incl. zero-row at index NN
#define NE 800000
#define FD 256
#define LD 128
#define BN_EPS 1e-5f
#define NEPAD (NE + 7 * NN + 16)
#define CNT_BLKS 3125   // NE/256
#define SCAN_BLKS 49    // ceil(NN/1024)
#define FILL_BLKS 1563  // ceil(NE/512)
#define ORD2_BLKS 98    // ceil(NN/512)
#define MG_BLKS 782     // 391 x 2 halves
#define FG_BLKS (FILL_BLKS + ORD2_BLKS + MG_BLKS)  // 2443

typedef __bf16 bf16_t;
typedef bf16_t bf16x8 __attribute__((ext_vector_type(8)));
typedef float f32x4 __attribute__((ext_vector_type(4)));
typedef float f32x2 __attribute__((ext_vector_type(2)));
typedef int i32x2 __attribute__((ext_vector_type(2)));
typedef int i32x4 __attribute__((ext_vector_type(4)));
typedef unsigned int u32x4 __attribute__((ext_vector_type(4)));
typedef unsigned short u16x8 __attribute__((ext_vector_type(8)));

// ---------------- D2: degree count || weight swizzle ----------------------
__global__ __launch_bounds__(256) void k_countw(
    const int* __restrict__ dst, int* __restrict__ cnt,
    const float* __restrict__ W0, const float* __restrict__ W1,
    const float* __restrict__ Wmu, const float* __restrict__ bmu,
    const float* __restrict__ Wlv, const float* __restrict__ blv,
    bf16_t* __restrict__ W0s, bf16_t* __restrict__ W1s,
    bf16_t* __restrict__ Whs, float* __restrict__ biash,
    bf16_t* __restrict__ g16, bf16_t* __restrict__ agg16) {
  int b = blockIdx.x, t = threadIdx.x;
  if (b < CNT_BLKS) {
    int i = b * 256 + t;
    if (i < NE) atomicAdd(&cnt[dst[i]], 1);
  } else {
    int k = b - CNT_BLKS, n = t;
    int chunk = (n >> 4) * 8 + (k >> 5);
    int slot = ((k >> 3) & 3) * 16 + (n & 15);
    int idx = chunk * 512 + slot * 8 + (k & 7);
    W0s[idx] = (bf16_t)W0[k * 256 + n];
    W1s[idx] = (bf16_t)W1[k * 256 + n];
    float wh = (n < 128) ? Wmu[k * 128 + n] : Wlv[k * 128 + (n - 128)];
    Whs[idx] = (bf16_t)wh;
    if (k == 0) biash[n] = (n < 128) ? bmu[n] : blv[n - 128];
    if (k == 1) {
      int ss = n >> 6, j = n & 63;
      g16[((size_t)ss * NP + NN) * 64 + j] = (bf16_t)0.f;
      agg16[((size_t)ss * NP + NN) * 64 + j] = (bf16_t)0.f;
    }
  }
}

// ---------------- D3: block-level padded scan + dinv ----------------------
__global__ __launch_bounds__(256) void k_scanA(const int* __restrict__ cnt,
                                               int* __restrict__ row_ptr,
                                               int* __restrict__ partials,
                                               float* __restrict__ dinv) {
  __shared__ int ws[4];
  int b = blockIdx.x, t = threadIdx.x;
  int base = b * 1024 + t * 4;
  int vals[4];
#pragma unroll
  for (int j = 0; j < 4; ++j) {
    int deg = (base + j < NN) ? cnt[base + j] : 0;
    vals[j] = (base + j < NN) ? ((deg + 7) & ~7) : 0;
    if (base + j < NN) dinv[base + j] = rsqrtf(1.0f + (float)deg);
  }
  int tsum = vals[0] + vals[1] + vals[2] + vals[3];
  int lane = t & 63, wid = t >> 6;
  int x = tsum;
#pragma unroll
  for (int off = 1; off < 64; off <<= 1) {
    int y = __shfl_up(x, off, 64);
    if (lane >= off) x += y;
  }
  if (lane == 63) ws[wid] = x;
  __syncthreads();
  int woff = 0;
  for (int w = 0; w < wid; ++w) woff += ws[w];
  int run = woff + x - tsum;
#pragma unroll
  for (int j = 0; j < 4; ++j) {
    if (base + j < NN) row_ptr[base + j] = run;
    run += vals[j];
  }
  if (t == 255) partials[b] = woff + x;
}

__global__ void k_scanB(int* __restrict__ partials, int* __restrict__ row_ptr) {
  int lane = threadIdx.x;
  int v = (lane < SCAN_BLKS) ? partials[lane] : 0;
  int x = v;
#pragma unroll
  for (int off = 1; off < 64; off <<= 1) {
    int y = __shfl_up(x, off, 64);
    if (lane >= off) x += y;
  }
  if (lane < SCAN_BLKS) partials[lane] = x - v;
  if (lane == SCAN_BLKS - 1) row_ptr[NN] = x;
}

// scanC: finalize row_ptr, PREFILL cursor with row_ptr, pad col slots,
// descending-degree histogram (LPT)
__global__ __launch_bounds__(256) void k_scanC(int* __restrict__ row_ptr,
                                               const int* __restrict__ partials,
                                               const int* __restrict__ cnt,
                                               int* __restrict__ cursor,
                                               unsigned short* __restrict__ col,
                                               int* __restrict__ hist) {
  __shared__ int lh[64];
  int b = blockIdx.x, t = threadIdx.x;
  if (t < 64) lh[t] = 0;
  __syncthreads();
  int off = partials[b];
  int base = b * 1024 + t * 4;
#pragma unroll
  for (int j = 0; j < 4; ++j)
    if (base + j < NN) {
      int deg = cnt[base + j];
      int rp = row_ptr[base + j] + off;
      row_ptr[base + j] = rp;
      cursor[base + j] = rp;  // absolute write cursor for fill
      int pd = (deg + 7) & ~7;
      for (int p = deg; p < pd; ++p) col[rp + p] = (unsigned short)NN;
      int it = pd >> 3;
      if (it > 63) it = 63;
      atomicAdd(&lh[63 - it], 1);  // descending bin (LPT)
    }
  __syncthreads();
  if (t < 64 && lh[t]) atomicAdd(&hist[t], lh[t]);
}

// ---------------- D4: fill || order || layer-0 mgemm (striped) ------------
// 512 threads. Role striping: every 3rd block (b%3==2, b/3<MG_BLKS) runs a
// layer-0 GEMM block; the rest map bijectively to fill then order. This
// co-schedules latency-bound fill with compute-bound GEMM on every CU.
// Fill chain is 2-deep: load dst -> atomicAdd(cursor) gives ABSOLUTE col pos.
__global__ __launch_bounds__(512) void k_fillgemm(
    const int* __restrict__ src, const int* __restrict__ dst,
    int* __restrict__ cursor, unsigned short* __restrict__ col,
    const int* __restrict__ cnt, const int* __restrict__ row_ptr,
    const float* __restrict__ dinv, const int* __restrict__ hist,
    int* __restrict__ rank, int* __restrict__ order, i32x2* __restrict__ desc,
    float* __restrict__ dinvp, const float* __restrict__ x,
    const bf16_t* __restrict__ W0s, bf16_t* __restrict__ g16) {
  __shared__ bf16_t Ws[64 * 512];  // 64 KB (mgemm role)
  const int nb = blockIdx.x, t = threadIdx.x;
  const bool isMg = (nb % 3 == 2) && (nb / 3) < MG_BLKS;
  if (!isMg) {
    int mgBefore = (nb + 1) / 3;
    if (mgBefore > MG_BLKS) mgBefore = MG_BLKS;
    int fo = nb - mgBefore;
    if (fo < FILL_BLKS) {
      // ---- fill ----
      int i = fo * 512 + t;
      if (i < NE) {
        int d = dst[i];
        int p = atomicAdd(&cursor[d], 1);  // absolute position
        col[p] = (unsigned short)src[i];
      }
    } else {
      // ---- order (degree-descending scatter) ----
      __shared__ int lcnt[64];
      __shared__ int gbase[64];
      __shared__ int sc[64];
      if (t < 64) {
        lcnt[t] = 0;
        int v = hist[t];
        int xx = v;
#pragma unroll
        for (int off = 1; off < 64; off <<= 1) {
          int y = __shfl_up(xx, off, 64);
          if (t >= off) xx += y;
        }
        sc[t] = xx - v;  // exclusive scan of descending bins
      }
      __syncthreads();
      int i = (fo - FILL_BLKS) * 512 + t;
      int bin = 0, rloc = 0, pd = 0;
      bool valid = (i < NN);
      if (valid) {
        pd = (cnt[i] + 7) & ~7;
        int it = pd >> 3;
        if (it > 63) it = 63;
        bin = 63 - it;
        rloc = atomicAdd(&lcnt[bin], 1);
      }
      __syncthreads();
      if (t < 64 && lcnt[t]) gbase[t] = sc[t] + atomicAdd(&rank[t], lcnt[t]);
      __syncthreads();
      if (valid) {
        int p = gbase[bin] + rloc;
        order[p] = i;
        int rp = row_ptr[i];
        desc[p] = (i32x2){rp, rp + pd};
        dinvp[p] = dinv[i];
      }
    }
    return;
  }
  // ---- layer-0 mgemm: g16 = rowscale(dinv) * bf16(x @ W0), superslice ----
  {
    int mb = nb / 3;
    int bx = mb >> 1, half = mb & 1;
    const bf16_t* srcW = W0s + (size_t)half * 64 * 512;
    bf16x8 wraw[8];
#pragma unroll
    for (int i = 0; i < 8; ++i)
      wraw[i] = *(const bf16x8*)&srcW[(i * 512 + t) * 8];
#pragma unroll
    for (int i = 0; i < 8; ++i) *(bf16x8*)&Ws[(i * 512 + t) * 8] = wraw[i];
    __syncthreads();

    const int wave = t >> 6, lane = t & 63;
    const int m = lane & 15, q = lane >> 4;
    const int row0 = bx * 128 + wave * 16;
    const int rg = row0 + m;
    const int rc = rg < NN ? rg : NN - 1;

    const float* p = x + (size_t)rc * 256 + q * 8;
    bf16x8 af[8];
    {
      float4 f0[8], f1[8];
#pragma unroll
      for (int kb = 0; kb < 8; ++kb) {
        f0[kb] = *(const float4*)(p + kb * 32);
        f1[kb] = *(const float4*)(p + kb * 32 + 4);
      }
#pragma unroll
      for (int kb = 0; kb < 8; ++kb) {
        bf16x8 fr;
        fr[0] = (bf16_t)f0[kb].x; fr[1] = (bf16_t)f0[kb].y;
        fr[2] = (bf16_t)f0[kb].z; fr[3] = (bf16_t)f0[kb].w;
        fr[4] = (bf16_t)f1[kb].x; fr[5] = (bf16_t)f1[kb].y;
        fr[6] = (bf16_t)f1[kb].z; fr[7] = (bf16_t)f1[kb].w;
        af[kb] = fr;
      }
    }

    f32x4 acc[8] = {};
#pragma unroll
    for (int nt = 0; nt < 8; ++nt) {
#pragma unroll
      for (int kb = 0; kb < 8; ++kb) {
        bf16x8 bfr = *(const bf16x8*)&Ws[(nt * 8 + kb) * 512 + lane * 8];
        acc[nt] = __builtin_amdgcn_mfma_f32_16x16x32_bf16(af[kb], bfr, acc[nt],
                                                          0, 0, 0);
      }
    }

#pragma unroll
    for (int r = 0; r < 4; ++r) {
      int row = row0 + q * 4 + r;
      if (row >= NN) continue;
      float rs = dinv[row];
#pragma unroll
      for (int nt = 0; nt < 8; ++nt) {
        int c = half * 128 + nt * 16 + m;
        g16[((size_t)(c >> 6) * NP + row) * 64 + (c & 63)] =
            (bf16_t)(acc[nt][r] * rs);
      }
    }
  }
}

// ---------------- MFMA GEMM: 512 threads, half-W staged in LDS ------------
// (layers 1 and heads) Block = 8 waves x 16 rows = 128 rows, half =
// blockIdx.y. BN finalize fused via stats.
__global__ __launch_bounds__(512) void k_mgemm(
    const void* __restrict__ Ap, const bf16_t* __restrict__ Wswz,
    bf16_t* __restrict__ Cb, float* __restrict__ Cf, int M,
    const float* __restrict__ stats, const float* __restrict__ gamma,
    const float* __restrict__ beta, const float* __restrict__ row_scale,
    const float* __restrict__ col_bias, int split) {
  __shared__ bf16_t Ws[64 * 512];  // 64 KB half-W
  __shared__ float bnsc_l[256], bnsh_l[256];
  const int tid = threadIdx.x;
  const int half = blockIdx.y;
  {
    const bf16_t* srcW = Wswz + (size_t)half * 64 * 512;
    bf16x8 wraw[8];
#pragma unroll
    for (int i = 0; i < 8; ++i)
      wraw[i] = *(const bf16x8*)&srcW[(i * 512 + tid) * 8];
#pragma unroll
    for (int i = 0; i < 8; ++i) *(bf16x8*)&Ws[(i * 512 + tid) * 8] = wraw[i];
  }
  if (tid < 256) {
    float mean = stats[tid] * (1.0f / NN);
    float var = stats[256 + tid] * (1.0f / NN) - mean * mean;
    float rs = rsqrtf(var + BN_EPS);
    float sc = gamma[tid] * rs;
    bnsc_l[tid] = sc;
    bnsh_l[tid] = beta[tid] - mean * sc;
  }
  __syncthreads();

  const int wave = tid >> 6, lane = tid & 63;
  const int m = lane & 15, q = lane >> 4;  // A-frag: row m, k-octet q
  const int row0 = blockIdx.x * 128 + wave * 16;
  const int rg = row0 + m;
  const int rc = rg < M ? rg : M - 1;

  const bf16_t* pA = (const bf16_t*)Ap;
  bf16x8 af[8];
  {
    bf16x8 raw[8];
#pragma unroll
    for (int kb = 0; kb < 8; ++kb)
      raw[kb] = *(const bf16x8*)&pA[((size_t)(kb >> 1) * NP + rc) * 64 +
                                    (kb & 1) * 32 + q * 8];
#pragma unroll
    for (int kb = 0; kb < 8; ++kb) {
      float s[8], h[8];
      float4 s0 = *(const float4*)&bnsc_l[kb * 32 + q * 8];
      float4 s1 = *(const float4*)&bnsc_l[kb * 32 + q * 8 + 4];
      float4 h0 = *(const float4*)&bnsh_l[kb * 32 + q * 8];
      float4 h1 = *(const float4*)&bnsh_l[kb * 32 + q * 8 + 4];
      s[0] = s0.x; s[1] = s0.y; s[2] = s0.z; s[3] = s0.w;
      s[4] = s1.x; s[5] = s1.y; s[6] = s1.z; s[7] = s1.w;
      h[0] = h0.x; h[1] = h0.y; h[2] = h0.z; h[3] = h0.w;
      h[4] = h1.x; h[5] = h1.y; h[6] = h1.z; h[7] = h1.w;
      bf16x8 r = raw[kb];
      bf16x8 fr;
#pragma unroll
      for (int j = 0; j < 8; ++j) {
        float v = (float)r[j];
        v = fmaxf(fmaf(v, s[j], h[j]), 0.f);
        fr[j] = (bf16_t)v;
      }
      af[kb] = fr;
    }
  }

  f32x4 acc[8] = {};
#pragma unroll
  for (int nt = 0; nt < 8; ++nt) {
#pragma unroll
    for (int kb = 0; kb < 8; ++kb) {
      bf16x8 b = *(const bf16x8*)&Ws[(nt * 8 + kb) * 512 + lane * 8];
      acc[nt] =
          __builtin_amdgcn_mfma_f32_16x16x32_bf16(af[kb], b, acc[nt], 0, 0, 0);
    }
  }

  // epilogue: D row_local = q*4 + r, col_local = m  [m89-verified layout]
#pragma unroll
  for (int r = 0; r < 4; ++r) {
    int row = row0 + q * 4 + r;
    if (row >= M) continue;
    float rs = row_scale ? row_scale[row] : 1.0f;
#pragma unroll
    for (int nt = 0; nt < 8; ++nt) {
      int col = half * 128 + nt * 16 + m;
      float v = acc[nt][r] * rs;
      if (col_bias) v += col_bias[col];
      if (Cb) {
        Cb[((size_t)(col >> 6) * NP + row) * 64 + (col & 63)] = (bf16_t)v;
      } else if (!split) {
        Cf[(size_t)row * 256 + col] = v;
      } else {
        if (col < 128)
          Cf[(size_t)row * 128 + col] = v;
        else
          Cf[(size_t)(M + row) * 128 + (col - 128)] = v;
      }
    }
  }
}

// ---------------- SpMM + fused BN stats, XCD-pair superslices -------------
// g / out superslice-major [4][NP][64]. slice = blockIdx.x & 3. Teams of 8
// lanes (16 B/lane -> ONE 128 B line per gather), TWO degree-sorted rows
// per team (DESCENDING degree: heavy blocks first = LPT). col is u16.
#define ACCUM8(A, d)                                             \
  A[0] += (f32x2){__uint_as_float(d[0] << 16),                   \
                  __uint_as_float(d[0] & 0xffff0000u)};          \
  A[1] += (f32x2){__uint_as_float(d[1] << 16),                   \
                  __uint_as_float(d[1] & 0xffff0000u)};          \
  A[2] += (f32x2){__uint_as_float(d[2] << 16),                   \
                  __uint_as_float(d[2] & 0xffff0000u)};          \
  A[3] += (f32x2){__uint_as_float(d[3] << 16),                   \
                  __uint_as_float(d[3] & 0xffff0000u)};

__global__ __launch_bounds__(256) void k_spmm(
    const bf16_t* __restrict__ g, const int* __restrict__ order,
    const i32x2* __restrict__ desc, const unsigned short* __restrict__ col,
    const float* __restrict__ dinvp, bf16_t* __restrict__ out,
    float* __restrict__ stats) {
  __shared__ float sbuf[32][64];
  const int s = blockIdx.x & 3;
  const int grp = blockIdx.x >> 2;
  const int team = threadIdx.x >> 3, tl = threadIdx.x & 7;
  const int slotA = grp * 64 + team * 2;  // even; NN even -> A,B same validity
  const u32x4* gu = (const u32x4*)(g + (size_t)s * NP * 64);  // node*8 + tl
  float s1[8] = {}, s2[8] = {};
  if (slotA < NN) {
    f32x2 accA[4] = {}, accB[4] = {};
    i32x2 o2 = *(const i32x2*)&order[slotA];
    i32x4 d4 = *(const i32x4*)&desc[slotA];
    f32x2 dv2 = *(const f32x2*)&dinvp[slotA];
    int dstA = o2[0], dstB = o2[1];
    int bA = d4[0], eA = d4[1], bB = d4[2], eB = d4[3];
    {
      u32x4 dA = gu[(size_t)dstA * 8 + tl];
      u32x4 dB = gu[(size_t)dstB * 8 + tl];
      ACCUM8(accA, dA)
      ACCUM8(accB, dB)
    }
    u16x8 cA = {}, cB = {};
    if (bA < eA) cA = __builtin_nontemporal_load((const u16x8*)&col[bA]);
    if (bB < eB) cB = __builtin_nontemporal_load((const u16x8*)&col[bB]);
    while (bA < eA && bB < eB) {
      u32x4 wa0 = gu[(size_t)cA[0] * 8 + tl];
      u32x4 wa1 = gu[(size_t)cA[1] * 8 + tl];
      u32x4 wa2 = gu[(size_t)cA[2] * 8 + tl];
      u32x4 wa3 = gu[(size_t)cA[3] * 8 + tl];
      u32x4 wa4 = gu[(size_t)cA[4] * 8 + tl];
      u32x4 wa5 = gu[(size_t)cA[5] * 8 + tl];
      u32x4 wa6 = gu[(size_t)cA[6] * 8 + tl];
      u32x4 wa7 = gu[(size_t)cA[7] * 8 + tl];
      u32x4 wb0 = gu[(size_t)cB[0] * 8 + tl];
      u32x4 wb1 = gu[(size_t)cB[1] * 8 + tl];
      u32x4 wb2 = gu[(size_t)cB[2] * 8 + tl];
      u32x4 wb3 = gu[(size_t)cB[3] * 8 + tl];
      u32x4 wb4 = gu[(size_t)cB[4] * 8 + tl];
      u32x4 wb5 = gu[(size_t)cB[5] * 8 + tl];
      u32x4 wb6 = gu[(size_t)cB[6] * 8 + tl];
      u32x4 wb7 = gu[(size_t)cB[7] * 8 + tl];
      int bnA = bA + 8, bnB = bB + 8;
      u16x8 cnA = {}, cnB = {};
      if (bnA < eA) cnA = __builtin_nontemporal_load((const u16x8*)&col[bnA]);
      if (bnB < eB) cnB = __builtin_nontemporal_load((const u16x8*)&col[bnB]);
      ACCUM8(accA, wa0) ACCUM8(accA, wa1) ACCUM8(accA, wa2) ACCUM8(accA, wa3)
      ACCUM8(accA, wa4) ACCUM8(accA, wa5) ACCUM8(accA, wa6) ACCUM8(accA, wa7)
      ACCUM8(accB, wb0) ACCUM8(accB, wb1) ACCUM8(accB, wb2) ACCUM8(accB, wb3)
      ACCUM8(accB, wb4) ACCUM8(accB, wb5) ACCUM8(accB, wb6) ACCUM8(accB, wb7)
      cA = cnA;
      cB = cnB;
      bA = bnA;
      bB = bnB;
    }
    while (bA < eA) {  // A tail
      u32x4 w0 = gu[(size_t)cA[0] * 8 + tl];
      u32x4 w1 = gu[(size_t)cA[1] * 8 + tl];
      u32x4 w2 = gu[(size_t)cA[2] * 8 + tl];
      u32x4 w3 = gu[(size_t)cA[3] * 8 + tl];
      u32x4 w4 = gu[(size_t)cA[4] * 8 + tl];
      u32x4 w5 = gu[(size_t)cA[5] * 8 + tl];
      u32x4 w6 = gu[(size_t)cA[6] * 8 + tl];
      u32x4 w7 = gu[(size_t)cA[7] * 8 + tl];
      int bn = bA + 8;
      u16x8 cn = {};
      if (bn < eA) cn = __builtin_nontemporal_load((const u16x8*)&col[bn]);
      ACCUM8(accA, w0) ACCUM8(accA, w1) ACCUM8(accA, w2) ACCUM8(accA, w3)
      ACCUM8(accA, w4) ACCUM8(accA, w5) ACCUM8(accA, w6) ACCUM8(accA, w7)
      cA = cn;
      bA = bn;
    }
    while (bB < eB) {  // B tail
      u32x4 w0 = gu[(size_t)cB[0] * 8 + tl];
      u32x4 w1 = gu[(size_t)cB[1] * 8 + tl];
      u32x4 w2 = gu[(size_t)cB[2] * 8 + tl];
      u32x4 w3 = gu[(size_t)cB[3] * 8 + tl];
      u32x4 w4 = gu[(size_t)cB[4] * 8 + tl];
      u32x4 w5 = gu[(size_t)cB[5] * 8 + tl];
      u32x4 w6 = gu[(size_t)cB[6] * 8 + tl];
      u32x4 w7 = gu[(size_t)cB[7] * 8 + tl];
      int bn = bB + 8;
      u16x8 cn = {};
      if (bn < eB) cn = __builtin_nontemporal_load((const u16x8*)&col[bn]);
      ACCUM8(accB, w0) ACCUM8(accB, w1) ACCUM8(accB, w2) ACCUM8(accB, w3)
      ACCUM8(accB, w4) ACCUM8(accB, w5) ACCUM8(accB, w6) ACCUM8(accB, w7)
      cB = cn;
      bB = bn;
    }
    float dvA = dv2[0], dvB = dv2[1];
    bf16x8 ovA, ovB;
#pragma unroll
    for (int j = 0; j < 8; ++j) {
      ovA[j] = (bf16_t)(accA[j >> 1][j & 1] * dvA);
      ovB[j] = (bf16_t)(accB[j >> 1][j & 1] * dvB);
    }
    __builtin_nontemporal_store(
        ovA, (bf16x8*)&out[((size_t)s * NP + dstA) * 64 + (size_t)tl * 8]);
    __builtin_nontemporal_store(
        ovB, (bf16x8*)&out[((size_t)s * NP + dstB) * 64 + (size_t)tl * 8]);
#pragma unroll
    for (int j = 0; j < 8; ++j) {
      float va = (float)ovA[j], vb = (float)ovB[j];
      s1[j] += va + vb;
      s2[j] = fmaf(va, va, s2[j]);
      s2[j] = fmaf(vb, vb, s2[j]);
    }
  }
  // block reduction of stats (64 feats of this slice across 32 teams)
#pragma unroll
  for (int j = 0; j < 8; ++j) sbuf[team][tl * 8 + j] = s1[j];
  __syncthreads();
  if (threadIdx.x < 64) {
    float tot = 0.f;
#pragma unroll
    for (int w = 0; w < 32; ++w) tot += sbuf[w][threadIdx.x];
    atomicAdd(&stats[s * 64 + threadIdx.x], tot);
  }
  __syncthreads();
#pragma unroll
  for (int j = 0; j < 8; ++j) sbuf[team][tl * 8 + j] = s2[j];
  __syncthreads();
  if (threadIdx.x < 64) {
    float tot = 0.f;
#pragma unroll
    for (int w = 0; w < 32; ++w) tot += sbuf[w][threadIdx.x];
    atomicAdd(&stats[256 + s * 64 + threadIdx.x], tot);
  }
}

// ---------------- launch ----------------
extern "C" void kernel_launch(void* const* d_in, const int* in_sizes, int n_in,
                              void* d_out, int out_size, void* d_ws, size_t ws_size,
                              hipStream_t stream) {
  const float* x = (const float*)d_in[0];
  const int* ei = (const int*)d_in[1];
  const int* esrc = ei;
  const int* edst = ei + NE;
  const float* W0 = (const float*)d_in[2];
  const float* gamma0 = (const float*)d_in[4];
  const float* beta0 = (const float*)d_in[5];
  const float* W1 = (const float*)d_in[6];
  const float* gamma1 = (const float*)d_in[8];
  const float* beta1 = (const float*)d_in[9];
  const float* W_mu = (const float*)d_in[10];
  const float* b_mu = (const float*)d_in[11];
  const float* W_lv = (const float*)d_in[12];
  const float* b_lv = (const float*)d_in[13];
  float* out = (float*)d_out;

  // workspace carve: cnt|cursor|statsAll|hist|rank contiguous -> one memset
  bf16_t* g16 = (bf16_t*)d_ws;                        // 4*NP*64 (superslice)
  bf16_t* agg16 = g16 + (size_t)4 * NP * 64;          // 4*NP*64 (superslice)
  int* cnt = (int*)(agg16 + (size_t)4 * NP * 64);     // NN
  int* cursor = cnt + NN;                             // NN
  float* statsAll = (float*)(cursor + NN);            // 1024 (2 layers x 512)
  int* hist = (int*)(statsAll + 1024);                // 64
  int* rank = hist + 64;                              // 64
  float* dinv = (float*)(rank + 64);                  // NN
  float* biash = dinv + NN;                           // 256
  bf16_t* W0s = (bf16_t*)(biash + 256);               // 65536 each
  bf16_t* W1s = W0s + 256 * 256;
  bf16_t* Whs = W1s + 256 * 256;
  int* row_ptr = (int*)(Whs + 256 * 256);             // NN+4
  int* order = row_ptr + NN + 4;                      // NN
  float* dinvp = (float*)(order + NN);                // NN
  i32x2* desc = (i32x2*)(dinvp + NN);                 // NN (8 B each)
  unsigned short* col = (unsigned short*)(desc + NN); // NEPAD u16 (16B align)
  int* partials = (int*)(col + NEPAD);                // 64

  hipMemsetAsync(cnt, 0, (2 * NN + 1024 + 128) * sizeof(int), stream);
  k_countw<<<CNT_BLKS + 256, 256, 0, stream>>>(edst, cnt, W0, W1, W_mu, b_mu,
                                               W_lv, b_lv, W0s, W1s, Whs,
                                               biash, g16, agg16);
  k_scanA<<<SCAN_BLKS, 256, 0, stream>>>(cnt, row_ptr, partials, dinv);
  k_scanB<<<1, 64, 0, stream>>>(partials, row_ptr);
  k_scanC<<<SCAN_BLKS, 256, 0, stream>>>(row_ptr, partials, cnt, cursor, col,
                                         hist);
  // fill || order || layer-0 mgemm (striped)
  k_fillgemm<<<FG_BLKS, 512, 0, stream>>>(esrc, edst, cursor, col, cnt,
                                          row_ptr, dinv, hist, rank, order,
                                          desc, dinvp, x, W0s, g16);

  dim3 gg((NN + 127) / 128, 2);  // 391 x 2, 512 threads, 128 rows/block
  const int SPMM_BLKS = 4 * ((NN + 63) / 64);  // 3128, slice = bid & 3

  k_spmm<<<SPMM_BLKS, 256, 0, stream>>>(g16, order, desc, col, dinvp, agg16,
                                        statsAll);

  // layer 1 (BN finalize of layer 0 fused into mgemm)
  k_mgemm<<<gg, 512, 0, stream>>>(agg16, W1s, g16, nullptr, NN, statsAll,
                                  gamma0, beta0, dinv, nullptr, 0);
  k_spmm<<<SPMM_BLKS, 256, 0, stream>>>(g16, order, desc, col, dinvp, agg16,
                                        statsAll + 512);

  // heads (fused mu|logvar; BN finalize of layer 1 fused)
  k_mgemm<<<gg, 512, 0, stream>>>(agg16, Whs, nullptr, out, NN, statsAll + 512,
                                  gamma1, beta1, nullptr, biash, 1);
}